// Round 4
// baseline (488.280 us; speedup 1.0000x reference)
//
#include <hip/hip_runtime.h>
#include <cstdint>
#include <cstddef>

static constexpr int Gn = 2;
static constexpr int Tn = 4096;
static constexpr int Hn = 2048;
static constexpr int En = 64;
static constexpr int CAPn = 128;
static constexpr size_t GT = (size_t)Gn * Tn;          // 8192
static constexpr size_t GTEC = GT * En * CAPn;         // 67,108,864

// ---------------------------------------------------------------------------
// Wave-level (64 lanes = 64 experts) softmax + top-2 + z-loss term, all f64.
// Tie-breaking on equal probs: lower expert index wins (matches lax.top_k).
// ---------------------------------------------------------------------------
__device__ inline void wave_softmax_topk(
    double logit, int g, int t,
    double* __restrict__ dkey, double* __restrict__ dlogz2,
    float* __restrict__ probs,
    int* __restrict__ idx0, int* __restrict__ idx1,
    float* __restrict__ g0f, float* __restrict__ g1f)
{
  const int e = threadIdx.x & 63;
  double m = logit;
  #pragma unroll
  for (int off = 32; off; off >>= 1) {
    double o = __shfl_xor(m, off);
    m = o > m ? o : m;
  }
  double ex = exp(logit - m);
  double s = ex;
  #pragma unroll
  for (int off = 32; off; off >>= 1) s += __shfl_xor(s, off);
  double p = ex / s;
  size_t gt = (size_t)g * Tn + t;
  probs[gt * En + e] = (float)p;

  // top-1 (value, index) with lower-index tie-break
  double bp = p; int bi = e;
  #pragma unroll
  for (int off = 32; off; off >>= 1) {
    double op = __shfl_xor(bp, off);
    int    oi = __shfl_xor(bi, off);
    if (op > bp || (op == bp && oi < bi)) { bp = op; bi = oi; }
  }
  // top-2: mask out top-1 lane
  double q = (e == bi) ? -1.0 : p;
  double bp2 = q; int bi2 = e;
  #pragma unroll
  for (int off = 32; off; off >>= 1) {
    double op = __shfl_xor(bp2, off);
    int    oi = __shfl_xor(bi2, off);
    if (op > bp2 || (op == bp2 && oi < bi2)) { bp2 = op; bi2 = oi; }
  }
  if (e == 0) {
    dkey[gt] = bp;                       // sort key = top-1 gate (f64)
    double lz = m + log(s);              // logsumexp
    dlogz2[gt] = lz * lz;
    idx0[gt] = bi;  idx1[gt] = bi2;
    g0f[gt] = (float)bp;  g1f[gt] = (float)bp2;
  }
}

// ---------------------------------------------------------------------------
// k0: convert W (f32 [H,E]) -> W64 (f64) once. Removes per-FMA cvt in k1.
// ---------------------------------------------------------------------------
__global__ __launch_bounds__(256) void k0_wcvt(
    const float* __restrict__ W, double* __restrict__ W64)
{
  int i = blockIdx.x * 256 + threadIdx.x;   // Hn*En = 131072 elements
  if (i < Hn * En) W64[i] = (double)W[i];
}

// ---------------------------------------------------------------------------
// k1 v3: logits + softmax + top2. LDS-FREE.
// 1024 waves (256 blocks x 4 waves); each wave owns 8 tokens; lane = expert.
// x row pointers are wave-uniform (readfirstlane) -> x reads go through the
// SCALAR pipe (s_load, scalar cache), leaving VMEM for the coalesced W64
// load (8 B/lane) and VALU for cvt+fma. No LDS unit pressure at all.
// Accumulation per token: h = 0..2047 strictly sequential (bit-identical
// f64 order to the validated R3 kernel -> same discrete decisions).
// ---------------------------------------------------------------------------
__global__ __launch_bounds__(256) void k1_gemm(
    const float* __restrict__ X, const double* __restrict__ W64,
    const float* __restrict__ Bv,
    double* __restrict__ dkey, double* __restrict__ dlogz2,
    float* __restrict__ probs,
    int* __restrict__ idx0, int* __restrict__ idx1,
    float* __restrict__ g0f, float* __restrict__ g1f)
{
  const int tid  = threadIdx.x;
  const int lane = tid & 63;
  const int wv   = __builtin_amdgcn_readfirstlane(tid >> 6);  // 0..3, SGPR
  const int wid  = blockIdx.x * 4 + wv;            // 0..1023, uniform
  const int g    = wid >> 9;                       // 512 waves per group
  const int t0   = (wid & 511) * 8;                // 8 tokens per wave

  const float* __restrict__ xr = X + ((size_t)g * Tn + t0) * Hn;  // uniform
  const double* __restrict__ wp = W64 + lane;

  double acc[8];
  #pragma unroll
  for (int j = 0; j < 8; ++j) acc[j] = 0.0;

  #pragma unroll 8
  for (int hh = 0; hh < Hn; ++hh) {
    double w = wp[(size_t)hh * En];                // coalesced VMEM (512 B)
    #pragma unroll
    for (int j = 0; j < 8; ++j) {
      acc[j] += (double)xr[(size_t)j * Hn + hh] * w;   // x via s_load
    }
  }

  const double bv = (double)Bv[lane];
  #pragma unroll
  for (int j = 0; j < 8; ++j) {
    wave_softmax_topk(acc[j] + bv, g, t0 + j,
                      dkey, dlogz2, probs, idx0, idx1, g0f, g1f);
  }
}

// ---------------------------------------------------------------------------
// k2: stable descending rank (== argsort(-gate0, stable)). O(T^2) compares,
// keys broadcast from LDS (unrolled x8 -> independent ds_reads pipeline).
// Scatters perm + expert ids into sorted order.
// ---------------------------------------------------------------------------
__global__ __launch_bounds__(256) void k2_rank(
    const double* __restrict__ dkey,
    const int* __restrict__ idx0, const int* __restrict__ idx1,
    int* __restrict__ perm, int* __restrict__ sidx0, int* __restrict__ sidx1)
{
  __shared__ double keys[Tn];                      // 32 KB
  const int tid = threadIdx.x;
  const int bid = blockIdx.x;
  const int g = bid >> 4;                          // 16 blocks per group
  const int part = bid & 15;
  const size_t gbase = (size_t)g * Tn;
  for (int i = tid; i < Tn; i += 256) keys[i] = dkey[gbase + i];
  __syncthreads();

  const int tg = part * 256 + tid;
  const double k = keys[tg];
  int r = 0;
  #pragma unroll 8
  for (int j = 0; j < Tn; ++j) {
    double kj = keys[j];
    r += (kj > k) || (kj == k && j < tg);          // stable, descending
  }
  perm[gbase + r]  = tg;
  sidx0[gbase + r] = idx0[gbase + tg];
  sidx1[gbase + r] = idx1[gbase + tg];
}

// ---------------------------------------------------------------------------
// k3: exact cumsum priorities. One wave per (g,e); scan sorted k=0 stream,
// then k=1 stream (flat order k*T + p), via ballot + popcount prefix.
// ---------------------------------------------------------------------------
__global__ __launch_bounds__(256) void k3_prio(
    const int* __restrict__ sidx0, const int* __restrict__ sidx1,
    const int* __restrict__ perm,
    int* __restrict__ prio0, int* __restrict__ prio1, int* __restrict__ cntge)
{
  const int tid  = threadIdx.x;
  const int wid  = (blockIdx.x * 256 + tid) >> 6;  // 0..127 = (g,e)
  const int lane = tid & 63;
  const int g = wid >> 6, e = wid & 63;
  const size_t gbase = (size_t)g * Tn;
  int cnt = 0;
  #pragma unroll 4
  for (int step = 0; step < Tn / 64; ++step) {
    int p = step * 64 + lane;
    bool mt = (sidx0[gbase + p] == e);
    unsigned long long mask = __ballot(mt);
    int pr = cnt + __popcll(mask & ((1ull << lane) - 1ull));
    if (mt) prio0[gbase + perm[gbase + p]] = pr;
    cnt += __popcll(mask);
  }
  #pragma unroll 4
  for (int step = 0; step < Tn / 64; ++step) {
    int p = step * 64 + lane;
    bool mt = (sidx1[gbase + p] == e);
    unsigned long long mask = __ballot(mt);
    int pr = cnt + __popcll(mask & ((1ull << lane) - 1ull));
    if (mt) prio1[gbase + perm[gbase + p]] = pr;
    cnt += __popcll(mask);
  }
  if (lane == 0) cntge[g * En + e] = cnt;          // tokens routed to (g,e)
}

// ---------------------------------------------------------------------------
// k4: per-(g,e) probability sums (deterministic: fixed lane strides + tree).
// ---------------------------------------------------------------------------
__global__ __launch_bounds__(256) void k4_sumprob(
    const float* __restrict__ probs, double* __restrict__ sumprob)
{
  const int tid  = threadIdx.x;
  const int wid  = (blockIdx.x * 256 + tid) >> 6;
  const int lane = tid & 63;
  const int g = wid >> 6, e = wid & 63;
  double s = 0.0;
  for (int i = 0; i < Tn / 64; ++i) {
    int t = i * 64 + lane;
    s += (double)probs[((size_t)g * Tn + t) * En + e];
  }
  #pragma unroll
  for (int off = 32; off; off >>= 1) s += __shfl_xor(s, off);
  if (lane == 0) sumprob[g * En + e] = s;
}

// ---------------------------------------------------------------------------
// k5: scalar losses (deterministic LDS tree reductions).
// ---------------------------------------------------------------------------
__global__ __launch_bounds__(256) void k5_scalars(
    const double* __restrict__ dlogz2, const double* __restrict__ sumprob,
    const int* __restrict__ cntge, float* __restrict__ out)
{
  __shared__ double red[256];
  const int tid = threadIdx.x;
  double z = 0.0;
  for (int i = tid; i < (int)GT; i += 256) z += dlogz2[i];
  red[tid] = z; __syncthreads();
  for (int s = 128; s; s >>= 1) { if (tid < s) red[tid] += red[tid + s]; __syncthreads(); }
  double zloss = red[0] / (double)GT;
  __syncthreads();

  double a = 0.0;
  if (tid < Gn * En) a = (double)cntge[tid] * sumprob[tid];
  red[tid] = a; __syncthreads();
  for (int s = 128; s; s >>= 1) { if (tid < s) red[tid] += red[tid + s]; __syncthreads(); }
  if (tid == 0) {
    // mean_{g,e}((cnt/T)*(sp/T)) * E^2  =  sum(cnt*sp) * E / (G*T*T)
    double aux = red[0] * (double)En / ((double)Gn * (double)Tn * (double)Tn);
    out[GTEC * 2]     = (float)aux;
    out[GTEC * 2 + 1] = (float)zloss;
  }
}

// ---------------------------------------------------------------------------
// k6: single-pass output writer. One block per token: zero-fill its [E,C]
// slab in dispatch + combine and insert the <=2 nonzeros. float4 coalesced.
// ---------------------------------------------------------------------------
__global__ __launch_bounds__(256) void k6_fill(
    const int* __restrict__ idx0, const int* __restrict__ idx1,
    const int* __restrict__ prio0, const int* __restrict__ prio1,
    const float* __restrict__ g0f, const float* __restrict__ g1f,
    float* __restrict__ out)
{
  const size_t gt = (size_t)blockIdx.x;            // 0..GT-1
  const int tid = threadIdx.x;
  const int e0 = idx0[gt], e1 = idx1[gt];
  const int p0 = prio0[gt], p1 = prio1[gt];
  const float v0 = g0f[gt], v1 = g1f[gt];
  const int n0 = (p0 < CAPn) ? e0 * CAPn + p0 : -1;
  const int n1 = (p1 < CAPn) ? e1 * CAPn + p1 : -1;
  const int q0 = n0 >> 2, q1 = n1 >> 2;            // -1 stays negative
  float4* disp = (float4*)(out + gt * (size_t)(En * CAPn));
  float4* comb = (float4*)(out + GTEC + gt * (size_t)(En * CAPn));
  #pragma unroll
  for (int i = 0; i < 8; ++i) {
    int q = tid + 256 * i;                         // 2048 float4 per array
    float4 v = {0.f, 0.f, 0.f, 0.f};
    float4 w = {0.f, 0.f, 0.f, 0.f};
    if (q == q0) { ((float*)&v)[n0 & 3] = 1.0f; ((float*)&w)[n0 & 3] = v0; }
    if (q == q1) { ((float*)&v)[n1 & 3] = 1.0f; ((float*)&w)[n1 & 3] = v1; }
    disp[q] = v;
    comb[q] = w;
  }
}

// ---------------------------------------------------------------------------
extern "C" void kernel_launch(void* const* d_in, const int* in_sizes, int n_in,
                              void* d_out, int out_size, void* d_ws, size_t ws_size,
                              hipStream_t stream)
{
  (void)in_sizes; (void)n_in; (void)out_size; (void)ws_size;
  const float* X  = (const float*)d_in[0];   // [G,T,H]
  const float* W  = (const float*)d_in[1];   // [H,E]
  const float* Bv = (const float*)d_in[2];   // [E]
  float* out = (float*)d_out;

  char* ws = (char*)d_ws;
  size_t off = 0;
  auto carve = [&](size_t bytes) -> void* {
    void* p = ws + off;
    off += (bytes + 255) & ~(size_t)255;
    return p;
  };
  double* W64    = (double*)carve((size_t)Hn * En * 8);   // 1 MB
  double* dkey   = (double*)carve(GT * 8);
  double* dlogz2 = (double*)carve(GT * 8);
  double* sumpr  = (double*)carve((size_t)Gn * En * 8);
  float*  probs  = (float*) carve(GT * En * 4);
  int* idx0  = (int*)carve(GT * 4);
  int* idx1  = (int*)carve(GT * 4);
  float* g0f = (float*)carve(GT * 4);
  float* g1f = (float*)carve(GT * 4);
  int* perm  = (int*)carve(GT * 4);
  int* sidx0 = (int*)carve(GT * 4);
  int* sidx1 = (int*)carve(GT * 4);
  int* prio0 = (int*)carve(GT * 4);
  int* prio1 = (int*)carve(GT * 4);
  int* cntge = (int*)carve((size_t)Gn * En * 4);

  k0_wcvt<<<(Hn * En + 255) / 256, 256, 0, stream>>>(W, W64);
  k1_gemm<<<256, 256, 0, stream>>>(X, W64, Bv, dkey, dlogz2, probs,
                                   idx0, idx1, g0f, g1f);
  k2_rank<<<Gn * 16, 256, 0, stream>>>(dkey, idx0, idx1, perm, sidx0, sidx1);
  k3_prio<<<(Gn * En) / 4, 256, 0, stream>>>(sidx0, sidx1, perm, prio0, prio1, cntge);
  k4_sumprob<<<(Gn * En) / 4, 256, 0, stream>>>(probs, sumpr);
  k5_scalars<<<1, 256, 0, stream>>>(dlogz2, sumpr, cntge, out);
  k6_fill<<<(int)GT, 256, 0, stream>>>(idx0, idx1, prio0, prio1, g0f, g1f, out);
}

// Round 6
// 319.517 us; speedup vs baseline: 1.5282x; 1.5282x over previous
//
#include <hip/hip_runtime.h>
#include <cstdint>
#include <cstddef>

static constexpr int Gn = 2;
static constexpr int Tn = 4096;
static constexpr int Hn = 2048;
static constexpr int En = 64;
static constexpr int CAPn = 128;
static constexpr size_t GT = (size_t)Gn * Tn;          // 8192
static constexpr size_t GTEC = GT * En * CAPn;         // 67,108,864

typedef float f4v __attribute__((ext_vector_type(4)));  // native vec for NT stores

// ---------------------------------------------------------------------------
// Wave-level (64 lanes = 64 experts) softmax + top-2 + z-loss term, all f64.
// Tie-breaking on equal probs: lower expert index wins (matches lax.top_k).
// ---------------------------------------------------------------------------
__device__ inline void wave_softmax_topk(
    double logit, int g, int t,
    double* __restrict__ dkey, double* __restrict__ dlogz2,
    float* __restrict__ probs,
    int* __restrict__ idx0, int* __restrict__ idx1,
    float* __restrict__ g0f, float* __restrict__ g1f)
{
  const int e = threadIdx.x & 63;
  double m = logit;
  #pragma unroll
  for (int off = 32; off; off >>= 1) {
    double o = __shfl_xor(m, off);
    m = o > m ? o : m;
  }
  double ex = exp(logit - m);
  double s = ex;
  #pragma unroll
  for (int off = 32; off; off >>= 1) s += __shfl_xor(s, off);
  double p = ex / s;
  size_t gt = (size_t)g * Tn + t;
  probs[gt * En + e] = (float)p;

  // top-1 (value, index) with lower-index tie-break
  double bp = p; int bi = e;
  #pragma unroll
  for (int off = 32; off; off >>= 1) {
    double op = __shfl_xor(bp, off);
    int    oi = __shfl_xor(bi, off);
    if (op > bp || (op == bp && oi < bi)) { bp = op; bi = oi; }
  }
  // top-2: mask out top-1 lane
  double q = (e == bi) ? -1.0 : p;
  double bp2 = q; int bi2 = e;
  #pragma unroll
  for (int off = 32; off; off >>= 1) {
    double op = __shfl_xor(bp2, off);
    int    oi = __shfl_xor(bi2, off);
    if (op > bp2 || (op == bp2 && oi < bi2)) { bp2 = op; bi2 = oi; }
  }
  if (e == 0) {
    dkey[gt] = bp;                       // sort key = top-1 gate (f64)
    double lz = m + log(s);              // logsumexp
    dlogz2[gt] = lz * lz;
    idx0[gt] = bi;  idx1[gt] = bi2;
    g0f[gt] = (float)bp;  g1f[gt] = (float)bp2;
  }
}

// ---------------------------------------------------------------------------
// k1 v5: logits + softmax + top2. No LDS, no scalar-pipe assumptions.
// 2048 waves (512 blocks x 4 waves), 2 waves/SIMD; lane = expert.
// Each wave owns 4 tokens. Per 16-h chunk:
//   - 1 coalesced x load: lane (j,hh) = j*16+hh holds x[t0+j][c*16+hh]
//   - 16 coalesced W f32 loads (512B each), cvt to f64 regs once
//   - 64 x { v_readlane (imm lane) + cvt + f64 fma }
// Broadcast of x is explicit via readlane -> no LDS unit, no SMEM gamble.
// h is accumulated strictly sequentially per token => decisions bit-match
// the validated R3/R4 runs.
// ---------------------------------------------------------------------------
__global__ __launch_bounds__(256) void k1_gemm(
    const float* __restrict__ X, const float* __restrict__ W,
    const float* __restrict__ Bv,
    double* __restrict__ dkey, double* __restrict__ dlogz2,
    float* __restrict__ probs,
    int* __restrict__ idx0, int* __restrict__ idx1,
    float* __restrict__ g0f, float* __restrict__ g1f)
{
  const int tid  = threadIdx.x;
  const int lane = tid & 63;
  const int w    = tid >> 6;
  const int wid  = blockIdx.x * 4 + w;             // 0..2047
  const int g    = wid >> 10;                      // 1024 waves per group
  const int t0   = (wid & 1023) * 4;               // 4 tokens per wave

  const float* __restrict__ xr = X + ((size_t)g * Tn + t0) * Hn;
  const int tj = lane >> 4;                        // which token this lane loads
  const int hj = lane & 15;                        // which h this lane loads

  double acc[4] = {0.0, 0.0, 0.0, 0.0};

  for (int c = 0; c < Hn / 16; ++c) {
    // x pack: lane v holds x[t0 + (v>>4)][c*16 + (v&15)]
    float xp = xr[(size_t)tj * Hn + c * 16 + hj];
    // W chunk into f64 regs (coalesced f32 loads, one cvt each)
    double wv[16];
    #pragma unroll
    for (int hh = 0; hh < 16; ++hh)
      wv[hh] = (double)W[(size_t)(c * 16 + hh) * En + lane];
    #pragma unroll
    for (int hh = 0; hh < 16; ++hh) {
      #pragma unroll
      for (int j = 0; j < 4; ++j) {
        float xs = __int_as_float(
            __builtin_amdgcn_readlane(__float_as_int(xp), j * 16 + hh));
        acc[j] = fma((double)xs, wv[hh], acc[j]);
      }
    }
  }

  const double bv = (double)Bv[lane];
  #pragma unroll
  for (int j = 0; j < 4; ++j) {
    wave_softmax_topk(acc[j] + bv, g, t0 + j,
                      dkey, dlogz2, probs, idx0, idx1, g0f, g1f);
  }
}

// ---------------------------------------------------------------------------
// k2 v2: stable descending rank, parallelized. 256 blocks; each block ranks
// 32 tokens against all Tn keys (staged once in LDS); 8 threads per token
// each scan 512 keys via b128 reads; integer partials summed exactly.
// ---------------------------------------------------------------------------
__global__ __launch_bounds__(256) void k2_rank(
    const double* __restrict__ dkey,
    const int* __restrict__ idx0, const int* __restrict__ idx1,
    int* __restrict__ perm, int* __restrict__ sidx0, int* __restrict__ sidx1)
{
  __shared__ __align__(16) double keys[Tn];        // 32 KB
  __shared__ int rk[32][8];
  const int tid = threadIdx.x;
  const int bid = blockIdx.x;
  const int g    = bid >> 7;                       // 128 blocks per group
  const int part = bid & 127;                      // 32 tokens per block
  const size_t gbase = (size_t)g * Tn;
  for (int i = tid; i < Tn; i += 256) keys[i] = dkey[gbase + i];
  __syncthreads();

  const int tl = tid >> 3;                         // token-local 0..31
  const int q  = tid & 7;                          // scan segment 0..7
  const int tg = part * 32 + tl;
  const double k = keys[tg];
  int r = 0;
  #pragma unroll 4
  for (int j2 = q * 512; j2 < q * 512 + 512; j2 += 2) {
    double2 kj = *(const double2*)&keys[j2];
    r += (kj.x > k) || (kj.x == k && (j2     < tg));
    r += (kj.y > k) || (kj.y == k && (j2 + 1 < tg));
  }
  rk[tl][q] = r;
  __syncthreads();
  if (tid < 32) {
    const int tg2 = part * 32 + tid;
    int rr = 0;
    #pragma unroll
    for (int u = 0; u < 8; ++u) rr += rk[tid][u];
    perm[gbase + rr]  = tg2;
    sidx0[gbase + rr] = idx0[gbase + tg2];
    sidx1[gbase + rr] = idx1[gbase + tg2];
  }
}

// ---------------------------------------------------------------------------
// k3 (fused with old k4): exact cumsum priorities + per-(g,e) prob sums.
// One wave per (g,e); ballot/popcount scan over sorted k=0 then k=1 stream.
// ---------------------------------------------------------------------------
__global__ __launch_bounds__(256) void k3_prio(
    const int* __restrict__ sidx0, const int* __restrict__ sidx1,
    const int* __restrict__ perm, const float* __restrict__ probs,
    int* __restrict__ prio0, int* __restrict__ prio1, int* __restrict__ cntge,
    double* __restrict__ sumprob)
{
  const int tid  = threadIdx.x;
  const int wid  = (blockIdx.x * 256 + tid) >> 6;  // 0..127 = (g,e)
  const int lane = tid & 63;
  const int g = wid >> 6, e = wid & 63;
  const size_t gbase = (size_t)g * Tn;
  int cnt = 0;
  #pragma unroll 4
  for (int step = 0; step < Tn / 64; ++step) {
    int p = step * 64 + lane;
    bool mt = (sidx0[gbase + p] == e);
    unsigned long long mask = __ballot(mt);
    int pr = cnt + __popcll(mask & ((1ull << lane) - 1ull));
    if (mt) prio0[gbase + perm[gbase + p]] = pr;
    cnt += __popcll(mask);
  }
  #pragma unroll 4
  for (int step = 0; step < Tn / 64; ++step) {
    int p = step * 64 + lane;
    bool mt = (sidx1[gbase + p] == e);
    unsigned long long mask = __ballot(mt);
    int pr = cnt + __popcll(mask & ((1ull << lane) - 1ull));
    if (mt) prio1[gbase + perm[gbase + p]] = pr;
    cnt += __popcll(mask);
  }
  if (lane == 0) cntge[g * En + e] = cnt;          // tokens routed to (g,e)

  // per-(g,e) probability sum (deterministic fixed-stride + butterfly)
  double s = 0.0;
  for (int i = 0; i < Tn / 64; ++i) {
    int t = i * 64 + lane;
    s += (double)probs[((size_t)g * Tn + t) * En + e];
  }
  #pragma unroll
  for (int off = 32; off; off >>= 1) s += __shfl_xor(s, off);
  if (lane == 0) sumprob[g * En + e] = s;
}

// ---------------------------------------------------------------------------
// k5: scalar losses (deterministic LDS tree reductions).
// ---------------------------------------------------------------------------
__global__ __launch_bounds__(256) void k5_scalars(
    const double* __restrict__ dlogz2, const double* __restrict__ sumprob,
    const int* __restrict__ cntge, float* __restrict__ out)
{
  __shared__ double red[256];
  const int tid = threadIdx.x;
  double z = 0.0;
  for (int i = tid; i < (int)GT; i += 256) z += dlogz2[i];
  red[tid] = z; __syncthreads();
  for (int s = 128; s; s >>= 1) { if (tid < s) red[tid] += red[tid + s]; __syncthreads(); }
  double zloss = red[0] / (double)GT;
  __syncthreads();

  double a = 0.0;
  if (tid < Gn * En) a = (double)cntge[tid] * sumprob[tid];
  red[tid] = a; __syncthreads();
  for (int s = 128; s; s >>= 1) { if (tid < s) red[tid] += red[tid + s]; __syncthreads(); }
  if (tid == 0) {
    // mean_{g,e}((cnt/T)*(sp/T)) * E^2  =  sum(cnt*sp) * E / (G*T*T)
    double aux = red[0] * (double)En / ((double)Gn * (double)Tn * (double)Tn);
    out[GTEC * 2]     = (float)aux;
    out[GTEC * 2 + 1] = (float)zloss;
  }
}

// ---------------------------------------------------------------------------
// k6: single-pass output writer. One block per token: zero-fill its [E,C]
// slab in dispatch + combine and insert the <=2 nonzeros. Nontemporal
// float4 stores (streaming, no reuse).
// ---------------------------------------------------------------------------
__global__ __launch_bounds__(256) void k6_fill(
    const int* __restrict__ idx0, const int* __restrict__ idx1,
    const int* __restrict__ prio0, const int* __restrict__ prio1,
    const float* __restrict__ g0f, const float* __restrict__ g1f,
    float* __restrict__ out)
{
  const size_t gt = (size_t)blockIdx.x;            // 0..GT-1
  const int tid = threadIdx.x;
  const int e0 = idx0[gt], e1 = idx1[gt];
  const int p0 = prio0[gt], p1 = prio1[gt];
  const float v0 = g0f[gt], v1 = g1f[gt];
  const int n0 = (p0 < CAPn) ? e0 * CAPn + p0 : -1;
  const int n1 = (p1 < CAPn) ? e1 * CAPn + p1 : -1;
  const int q0 = n0 >> 2, q1 = n1 >> 2;            // -1 stays negative
  f4v* disp = (f4v*)(out + gt * (size_t)(En * CAPn));
  f4v* comb = (f4v*)(out + GTEC + gt * (size_t)(En * CAPn));
  #pragma unroll
  for (int i = 0; i < 8; ++i) {
    int q = tid + 256 * i;                         // 2048 float4 per array
    f4v v = {0.f, 0.f, 0.f, 0.f};
    f4v w = {0.f, 0.f, 0.f, 0.f};
    if (q == q0) { v[n0 & 3] = 1.0f; w[n0 & 3] = v0; }
    if (q == q1) { v[n1 & 3] = 1.0f; w[n1 & 3] = v1; }
    __builtin_nontemporal_store(v, &disp[q]);
    __builtin_nontemporal_store(w, &comb[q]);
  }
}

// ---------------------------------------------------------------------------
extern "C" void kernel_launch(void* const* d_in, const int* in_sizes, int n_in,
                              void* d_out, int out_size, void* d_ws, size_t ws_size,
                              hipStream_t stream)
{
  (void)in_sizes; (void)n_in; (void)out_size; (void)ws_size;
  const float* X  = (const float*)d_in[0];   // [G,T,H]
  const float* W  = (const float*)d_in[1];   // [H,E]
  const float* Bv = (const float*)d_in[2];   // [E]
  float* out = (float*)d_out;

  char* ws = (char*)d_ws;
  size_t off = 0;
  auto carve = [&](size_t bytes) -> void* {
    void* p = ws + off;
    off += (bytes + 255) & ~(size_t)255;
    return p;
  };
  double* dkey   = (double*)carve(GT * 8);
  double* dlogz2 = (double*)carve(GT * 8);
  double* sumpr  = (double*)carve((size_t)Gn * En * 8);
  float*  probs  = (float*) carve(GT * En * 4);
  int* idx0  = (int*)carve(GT * 4);
  int* idx1  = (int*)carve(GT * 4);
  float* g0f = (float*)carve(GT * 4);
  float* g1f = (float*)carve(GT * 4);
  int* perm  = (int*)carve(GT * 4);
  int* sidx0 = (int*)carve(GT * 4);
  int* sidx1 = (int*)carve(GT * 4);
  int* prio0 = (int*)carve(GT * 4);
  int* prio1 = (int*)carve(GT * 4);
  int* cntge = (int*)carve((size_t)Gn * En * 4);

  k1_gemm<<<512, 256, 0, stream>>>(X, W, Bv, dkey, dlogz2, probs,
                                   idx0, idx1, g0f, g1f);
  k2_rank<<<Gn * 128, 256, 0, stream>>>(dkey, idx0, idx1, perm, sidx0, sidx1);
  k3_prio<<<(Gn * En) / 4, 256, 0, stream>>>(sidx0, sidx1, perm, probs,
                                             prio0, prio1, cntge, sumpr);
  k5_scalars<<<1, 256, 0, stream>>>(dlogz2, sumpr, cntge, out);
  k6_fill<<<(int)GT, 256, 0, stream>>>(idx0, idx1, prio0, prio1, g0f, g1f, out);
}

// Round 7
// 276.438 us; speedup vs baseline: 1.7663x; 1.1558x over previous
//
#include <hip/hip_runtime.h>
#include <cstdint>
#include <cstddef>

static constexpr int Gn = 2;
static constexpr int Tn = 4096;
static constexpr int Hn = 2048;
static constexpr int En = 64;
static constexpr int CAPn = 128;
static constexpr size_t GT = (size_t)Gn * Tn;          // 8192
static constexpr size_t GTEC = GT * En * CAPn;         // 67,108,864

typedef float f4v __attribute__((ext_vector_type(4)));  // native vec for NT stores

// ---------------------------------------------------------------------------
// Wave-level (64 lanes = 64 experts) softmax + top-2 + z-loss term, all f64.
// Returns p (this lane's expert probability) for the caller's aux-loss sum.
// Tie-breaking on equal probs: lower expert index wins (matches lax.top_k).
// ---------------------------------------------------------------------------
__device__ inline double wave_softmax_topk(
    double logit, int g, int t,
    double* __restrict__ dkey, double* __restrict__ dlogz2,
    int* __restrict__ idx0, int* __restrict__ idx1,
    float* __restrict__ g0f, float* __restrict__ g1f)
{
  const int e = threadIdx.x & 63;
  double m = logit;
  #pragma unroll
  for (int off = 32; off; off >>= 1) {
    double o = __shfl_xor(m, off);
    m = o > m ? o : m;
  }
  double ex = exp(logit - m);
  double s = ex;
  #pragma unroll
  for (int off = 32; off; off >>= 1) s += __shfl_xor(s, off);
  double p = ex / s;
  size_t gt = (size_t)g * Tn + t;

  // top-1 (value, index) with lower-index tie-break
  double bp = p; int bi = e;
  #pragma unroll
  for (int off = 32; off; off >>= 1) {
    double op = __shfl_xor(bp, off);
    int    oi = __shfl_xor(bi, off);
    if (op > bp || (op == bp && oi < bi)) { bp = op; bi = oi; }
  }
  // top-2: mask out top-1 lane
  double q = (e == bi) ? -1.0 : p;
  double bp2 = q; int bi2 = e;
  #pragma unroll
  for (int off = 32; off; off >>= 1) {
    double op = __shfl_xor(bp2, off);
    int    oi = __shfl_xor(bi2, off);
    if (op > bp2 || (op == bp2 && oi < bi2)) { bp2 = op; bi2 = oi; }
  }
  if (e == 0) {
    dkey[gt] = bp;                       // sort key = top-1 gate (f64)
    double lz = m + log(s);              // logsumexp
    dlogz2[gt] = lz * lz;
    idx0[gt] = bi;  idx1[gt] = bi2;
    g0f[gt] = (float)bp;  g1f[gt] = (float)bp2;
  }
  return p;
}

// ---------------------------------------------------------------------------
// k1 v6: logits + softmax + top2 + per-block prob-sum partials.
// 2048 waves (512 blocks x 4 waves), 2 waves/SIMD; lane = expert.
// Each wave owns 4 tokens. Per 16-h chunk:
//   - 1 coalesced x load; 16 coalesced W f32 loads (cvt to f64 once)
//   - 64 x { v_readlane (imm lane) + cvt + f64 fma }
// h strictly sequential per token => decisions bit-match passing R6 run.
// New: psum (f64 sum of p over the wave's 4 tokens) -> LDS reduce over the
// block's 4 waves -> partial[block][e]  (replaces transposed probs reads).
// ---------------------------------------------------------------------------
__global__ __launch_bounds__(256) void k1_gemm(
    const float* __restrict__ X, const float* __restrict__ W,
    const float* __restrict__ Bv,
    double* __restrict__ dkey, double* __restrict__ dlogz2,
    int* __restrict__ idx0, int* __restrict__ idx1,
    float* __restrict__ g0f, float* __restrict__ g1f,
    double* __restrict__ partial)
{
  __shared__ double red[4][64];
  const int tid  = threadIdx.x;
  const int lane = tid & 63;
  const int w    = tid >> 6;
  const int wid  = blockIdx.x * 4 + w;             // 0..2047
  const int g    = wid >> 10;                      // 1024 waves per group
  const int t0   = (wid & 1023) * 4;               // 4 tokens per wave

  const float* __restrict__ xr = X + ((size_t)g * Tn + t0) * Hn;
  const int tj = lane >> 4;                        // which token this lane loads
  const int hj = lane & 15;                        // which h this lane loads

  double acc[4] = {0.0, 0.0, 0.0, 0.0};

  for (int c = 0; c < Hn / 16; ++c) {
    // x pack: lane v holds x[t0 + (v>>4)][c*16 + (v&15)]
    float xp = xr[(size_t)tj * Hn + c * 16 + hj];
    // W chunk into f64 regs (coalesced f32 loads, one cvt each)
    double wv[16];
    #pragma unroll
    for (int hh = 0; hh < 16; ++hh)
      wv[hh] = (double)W[(size_t)(c * 16 + hh) * En + lane];
    #pragma unroll
    for (int hh = 0; hh < 16; ++hh) {
      #pragma unroll
      for (int j = 0; j < 4; ++j) {
        float xs = __int_as_float(
            __builtin_amdgcn_readlane(__float_as_int(xp), j * 16 + hh));
        acc[j] = fma((double)xs, wv[hh], acc[j]);
      }
    }
  }

  const double bv = (double)Bv[lane];
  double psum = 0.0;
  #pragma unroll
  for (int j = 0; j < 4; ++j) {
    psum += wave_softmax_topk(acc[j] + bv, g, t0 + j,
                              dkey, dlogz2, idx0, idx1, g0f, g1f);
  }
  red[w][lane] = psum;
  __syncthreads();
  if (tid < 64) {
    double s = red[0][tid] + red[1][tid] + red[2][tid] + red[3][tid];
    partial[(size_t)blockIdx.x * 64 + tid] = s;    // coalesced 512B
  }
}

// ---------------------------------------------------------------------------
// k2: stable descending rank, parallelized. 256 blocks; each block ranks
// 32 tokens against all Tn keys (staged once in LDS); 8 threads per token
// each scan 512 keys via b128 reads; integer partials summed exactly.
// ---------------------------------------------------------------------------
__global__ __launch_bounds__(256) void k2_rank(
    const double* __restrict__ dkey,
    const int* __restrict__ idx0, const int* __restrict__ idx1,
    int* __restrict__ perm, int* __restrict__ sidx0, int* __restrict__ sidx1)
{
  __shared__ __align__(16) double keys[Tn];        // 32 KB
  __shared__ int rk[32][8];
  const int tid = threadIdx.x;
  const int bid = blockIdx.x;
  const int g    = bid >> 7;                       // 128 blocks per group
  const int part = bid & 127;                      // 32 tokens per block
  const size_t gbase = (size_t)g * Tn;
  for (int i = tid; i < Tn; i += 256) keys[i] = dkey[gbase + i];
  __syncthreads();

  const int tl = tid >> 3;                         // token-local 0..31
  const int q  = tid & 7;                          // scan segment 0..7
  const int tg = part * 32 + tl;
  const double k = keys[tg];
  int r = 0;
  #pragma unroll 4
  for (int j2 = q * 512; j2 < q * 512 + 512; j2 += 2) {
    double2 kj = *(const double2*)&keys[j2];
    r += (kj.x > k) || (kj.x == k && (j2     < tg));
    r += (kj.y > k) || (kj.y == k && (j2 + 1 < tg));
  }
  rk[tl][q] = r;
  __syncthreads();
  if (tid < 32) {
    const int tg2 = part * 32 + tid;
    int rr = 0;
    #pragma unroll
    for (int u = 0; u < 8; ++u) rr += rk[tid][u];
    perm[gbase + rr]  = tg2;
    sidx0[gbase + rr] = idx0[gbase + tg2];
    sidx1[gbase + rr] = idx1[gbase + tg2];
  }
}

// ---------------------------------------------------------------------------
// k3 v2: exact cumsum priorities, block-parallel. One BLOCK per (g,e):
// 128 blocks x 256 threads. Each thread counts matches in its 16 consecutive
// sorted positions; Hillis-Steele block scan gives exclusive offsets; second
// pass assigns priorities (k=0 stream, then k=1 continuing the count —
// identical integers to the sequential ballot scan).
// ---------------------------------------------------------------------------
__global__ __launch_bounds__(256) void k3_prio(
    const int* __restrict__ sidx0, const int* __restrict__ sidx1,
    const int* __restrict__ perm,
    int* __restrict__ prio0, int* __restrict__ prio1, int* __restrict__ cntge)
{
  __shared__ int sc[256];
  const int tid = threadIdx.x;
  const int g = blockIdx.x >> 6;
  const int e = blockIdx.x & 63;
  const size_t gbase = (size_t)g * Tn;
  const int p0 = tid * 16;

  int base = 0;
  #pragma unroll
  for (int ph = 0; ph < 2; ++ph) {
    const int* __restrict__ sidx = ph ? sidx1 : sidx0;
    int* __restrict__ prio = ph ? prio1 : prio0;

    int loc[16];
    const int4* s4 = (const int4*)(sidx + gbase + p0);
    #pragma unroll
    for (int u = 0; u < 4; ++u) {
      int4 v = s4[u];
      loc[u * 4 + 0] = v.x; loc[u * 4 + 1] = v.y;
      loc[u * 4 + 2] = v.z; loc[u * 4 + 3] = v.w;
    }
    int cntl = 0;
    #pragma unroll
    for (int k = 0; k < 16; ++k) cntl += (loc[k] == e);

    __syncthreads();                   // protect sc reuse across phases
    sc[tid] = cntl;
    __syncthreads();
    #pragma unroll
    for (int off = 1; off < 256; off <<= 1) {
      int v = (tid >= off) ? sc[tid - off] : 0;
      __syncthreads();
      sc[tid] += v;
      __syncthreads();
    }
    int pr = base + sc[tid] - cntl;    // exclusive prefix + phase base
    int total = sc[255];
    #pragma unroll
    for (int k = 0; k < 16; ++k) {
      if (loc[k] == e) {
        prio[gbase + perm[gbase + p0 + k]] = pr;
        ++pr;
      }
    }
    base += total;
  }
  if (tid == 0) cntge[g * En + e] = base;
}

// ---------------------------------------------------------------------------
// k5a: per-group partials. Block g: zpart = sum(dlogz2[g]), auxpart =
// sum_e( cntge[g][e] * sum_b partial[b][e] ). Deterministic fixed trees.
// ---------------------------------------------------------------------------
__global__ __launch_bounds__(256) void k5a(
    const double* __restrict__ dlogz2, const double* __restrict__ partial,
    const int* __restrict__ cntge, double* __restrict__ gpart)
{
  __shared__ double red[256];
  const int g = blockIdx.x;
  const int tid = threadIdx.x;

  double z = 0.0;
  for (int i = tid; i < Tn; i += 256) z += dlogz2[(size_t)g * Tn + i];
  red[tid] = z; __syncthreads();
  for (int s = 128; s; s >>= 1) { if (tid < s) red[tid] += red[tid + s]; __syncthreads(); }
  if (tid == 0) gpart[g * 2 + 0] = red[0];
  __syncthreads();

  // sum partial over this group's 256 k1-blocks (coalesced 2KB per iter)
  const int q = tid >> 6, e = tid & 63;
  double s = 0.0;
  for (int i = 0; i < 64; ++i) {
    int b = g * 256 + i * 4 + q;
    s += partial[(size_t)b * 64 + e];
  }
  red[tid] = s; __syncthreads();
  if (tid < 64) {
    double sp = red[tid] + red[64 + tid] + red[128 + tid] + red[192 + tid];
    red[tid] = sp * (double)cntge[g * En + tid];
  }
  __syncthreads();
  for (int st = 32; st; st >>= 1) { if (tid < st) red[tid] += red[tid + st]; __syncthreads(); }
  if (tid == 0) gpart[g * 2 + 1] = red[0];
}

// ---------------------------------------------------------------------------
// k6: single-pass output writer. One block per token: zero-fill its [E,C]
// slab in dispatch + combine, insert the <=2 nonzeros (NT float4 stores).
// Block 0 / thread 0 additionally finalizes the two scalar losses.
// ---------------------------------------------------------------------------
__global__ __launch_bounds__(256) void k6_fill(
    const int* __restrict__ idx0, const int* __restrict__ idx1,
    const int* __restrict__ prio0, const int* __restrict__ prio1,
    const float* __restrict__ g0f, const float* __restrict__ g1f,
    const double* __restrict__ gpart,
    float* __restrict__ out)
{
  const size_t gt = (size_t)blockIdx.x;            // 0..GT-1
  const int tid = threadIdx.x;
  const int e0 = idx0[gt], e1 = idx1[gt];
  const int p0 = prio0[gt], p1 = prio1[gt];
  const float v0 = g0f[gt], v1 = g1f[gt];
  const int n0 = (p0 < CAPn) ? e0 * CAPn + p0 : -1;
  const int n1 = (p1 < CAPn) ? e1 * CAPn + p1 : -1;
  const int q0 = n0 >> 2, q1 = n1 >> 2;            // -1 stays negative
  f4v* disp = (f4v*)(out + gt * (size_t)(En * CAPn));
  f4v* comb = (f4v*)(out + GTEC + gt * (size_t)(En * CAPn));
  #pragma unroll
  for (int i = 0; i < 8; ++i) {
    int q = tid + 256 * i;                         // 2048 float4 per array
    f4v v = {0.f, 0.f, 0.f, 0.f};
    f4v w = {0.f, 0.f, 0.f, 0.f};
    if (q == q0) { v[n0 & 3] = 1.0f; w[n0 & 3] = v0; }
    if (q == q1) { v[n1 & 3] = 1.0f; w[n1 & 3] = v1; }
    __builtin_nontemporal_store(v, &disp[q]);
    __builtin_nontemporal_store(w, &comb[q]);
  }
  if (gt == 0 && tid == 0) {
    double aux = (gpart[1] + gpart[3]) * (double)En /
                 ((double)Gn * (double)Tn * (double)Tn);
    double z   = (gpart[0] + gpart[2]) / (double)GT;
    out[GTEC * 2]     = (float)aux;
    out[GTEC * 2 + 1] = (float)z;
  }
}

// ---------------------------------------------------------------------------
extern "C" void kernel_launch(void* const* d_in, const int* in_sizes, int n_in,
                              void* d_out, int out_size, void* d_ws, size_t ws_size,
                              hipStream_t stream)
{
  (void)in_sizes; (void)n_in; (void)out_size; (void)ws_size;
  const float* X  = (const float*)d_in[0];   // [G,T,H]
  const float* W  = (const float*)d_in[1];   // [H,E]
  const float* Bv = (const float*)d_in[2];   // [E]
  float* out = (float*)d_out;

  char* ws = (char*)d_ws;
  size_t off = 0;
  auto carve = [&](size_t bytes) -> void* {
    void* p = ws + off;
    off += (bytes + 255) & ~(size_t)255;
    return p;
  };
  double* dkey    = (double*)carve(GT * 8);
  double* dlogz2  = (double*)carve(GT * 8);
  double* partial = (double*)carve((size_t)512 * 64 * 8);  // 256 KB
  double* gpart   = (double*)carve(4 * 8);
  int* idx0  = (int*)carve(GT * 4);
  int* idx1  = (int*)carve(GT * 4);
  float* g0f = (float*)carve(GT * 4);
  float* g1f = (float*)carve(GT * 4);
  int* perm  = (int*)carve(GT * 4);
  int* sidx0 = (int*)carve(GT * 4);
  int* sidx1 = (int*)carve(GT * 4);
  int* prio0 = (int*)carve(GT * 4);
  int* prio1 = (int*)carve(GT * 4);
  int* cntge = (int*)carve((size_t)Gn * En * 4);

  k1_gemm<<<512, 256, 0, stream>>>(X, W, Bv, dkey, dlogz2,
                                   idx0, idx1, g0f, g1f, partial);
  k2_rank<<<Gn * 128, 256, 0, stream>>>(dkey, idx0, idx1, perm, sidx0, sidx1);
  k3_prio<<<Gn * En, 256, 0, stream>>>(sidx0, sidx1, perm, prio0, prio1, cntge);
  k5a<<<Gn, 256, 0, stream>>>(dlogz2, partial, cntge, gpart);
  k6_fill<<<(int)GT, 256, 0, stream>>>(idx0, idx1, prio0, prio1, g0f, g1f,
                                       gpart, out);
}

// Round 8
// 178.540 us; speedup vs baseline: 2.7349x; 1.5483x over previous
//
#include <hip/hip_runtime.h>
#include <cstdint>
#include <cstddef>

static constexpr int Gn = 2;
static constexpr int Tn = 4096;
static constexpr int Hn = 2048;
static constexpr int En = 64;
static constexpr int CAPn = 128;
static constexpr size_t GT = (size_t)Gn * Tn;          // 8192
static constexpr size_t GTEC = GT * En * CAPn;         // 67,108,864
static constexpr size_t GTEC4 = GTEC / 4;              // float4 units

typedef float f4v __attribute__((ext_vector_type(4)));  // native vec for NT stores

// ---------------------------------------------------------------------------
// Wave-level (64 lanes = 64 experts) softmax + top-2 + z-loss term, all f64.
// Returns p (this lane's expert probability) for the caller's aux-loss sum.
// Tie-breaking on equal probs: lower expert index wins (matches lax.top_k).
// ---------------------------------------------------------------------------
__device__ inline double wave_softmax_topk(
    double logit, int g, int t,
    double* __restrict__ dkey, double* __restrict__ dlogz2,
    int* __restrict__ idx0, int* __restrict__ idx1,
    float* __restrict__ g0f, float* __restrict__ g1f)
{
  const int e = threadIdx.x & 63;
  double m = logit;
  #pragma unroll
  for (int off = 32; off; off >>= 1) {
    double o = __shfl_xor(m, off);
    m = o > m ? o : m;
  }
  double ex = exp(logit - m);
  double s = ex;
  #pragma unroll
  for (int off = 32; off; off >>= 1) s += __shfl_xor(s, off);
  double p = ex / s;
  size_t gt = (size_t)g * Tn + t;

  // top-1 (value, index) with lower-index tie-break
  double bp = p; int bi = e;
  #pragma unroll
  for (int off = 32; off; off >>= 1) {
    double op = __shfl_xor(bp, off);
    int    oi = __shfl_xor(bi, off);
    if (op > bp || (op == bp && oi < bi)) { bp = op; bi = oi; }
  }
  // top-2: mask out top-1 lane
  double q = (e == bi) ? -1.0 : p;
  double bp2 = q; int bi2 = e;
  #pragma unroll
  for (int off = 32; off; off >>= 1) {
    double op = __shfl_xor(bp2, off);
    int    oi = __shfl_xor(bi2, off);
    if (op > bp2 || (op == bp2 && oi < bi2)) { bp2 = op; bi2 = oi; }
  }
  if (e == 0) {
    dkey[gt] = bp;                       // sort key = top-1 gate (f64)
    double lz = m + log(s);              // logsumexp
    dlogz2[gt] = lz * lz;
    idx0[gt] = bi;  idx1[gt] = bi2;
    g0f[gt] = (float)bp;  g1f[gt] = (float)bp2;
  }
  return p;
}

// ---------------------------------------------------------------------------
// k1 v7: logits + softmax + top2 + prob-sum partials + OUTPUT ZERO-FILL.
// 1024 blocks x 4 waves (4 waves/SIMD). Block owns 8 tokens. Wave w:
// token quad qd=w&1 (4 tokens), H-half hf=w>>1 (1024 h). Halves combine
// via one LDS add (half0+half1) before softmax — f64 noise ~1e-16 vs
// decision gaps ~1e-7, verified-safe regime.
// Per 16-h chunk: 1 coalesced x load, 16 W f32 loads (cvt once), 64 x
// {readlane + cvt + fma}, and 2 nontemporal zero-stores to the output
// slabs (overlaps the 512 MB zero-fill with compute; k6 only scatters).
// ---------------------------------------------------------------------------
__global__ __launch_bounds__(256, 4) void k1_gemm(
    const float* __restrict__ X, const float* __restrict__ W,
    const float* __restrict__ Bv,
    double* __restrict__ dkey, double* __restrict__ dlogz2,
    int* __restrict__ idx0, int* __restrict__ idx1,
    float* __restrict__ g0f, float* __restrict__ g1f,
    double* __restrict__ partial, float* __restrict__ out)
{
  __shared__ double red[4][4][64];                 // 8 KB
  const int tid  = threadIdx.x;
  const int lane = tid & 63;
  const int w    = tid >> 6;
  const int qd   = w & 1;                          // token quad
  const int hf   = w >> 1;                         // H half
  const int bid  = blockIdx.x;
  const int g    = bid >> 9;                       // 512 blocks per group
  const int tb   = (bid & 511) * 8;                // block's first token
  const int t0   = tb + qd * 4;                    // wave's first token
  const size_t gt0 = (size_t)g * Tn + tb;          // block's first global token

  const float* __restrict__ xr = X + ((size_t)g * Tn + t0) * Hn + hf * 1024;
  const float* __restrict__ wp = W + (size_t)(hf * 1024) * En + lane;
  const int tj = lane >> 4;                        // token this lane loads
  const int hj = lane & 15;                        // h this lane loads

  f4v* __restrict__ ob = (f4v*)out;
  const f4v zf = {0.f, 0.f, 0.f, 0.f};

  double acc[4] = {0.0, 0.0, 0.0, 0.0};

  for (int c = 0; c < 64; ++c) {                   // 64 chunks x 16 h
    // zero-fill: 2 coalesced NT stores/thread/chunk covers block's slabs
    {
      int n1 = c * 512 + tid;                      // [0, 32768)
      int n2 = n1 + 256;
      int a1 = n1 >> 14, r1 = n1 & 16383;
      int a2 = n2 >> 14, r2 = n2 & 16383;
      size_t i1 = (size_t)a1 * GTEC4 + (gt0 + (r1 >> 11)) * 2048 + (r1 & 2047);
      size_t i2 = (size_t)a2 * GTEC4 + (gt0 + (r2 >> 11)) * 2048 + (r2 & 2047);
      __builtin_nontemporal_store(zf, &ob[i1]);
      __builtin_nontemporal_store(zf, &ob[i2]);
    }
    // x pack: lane v holds x[t0 + (v>>4)][hf*1024 + c*16 + (v&15)]
    float xp = xr[(size_t)tj * Hn + c * 16 + hj];
    // W chunk into f64 regs (coalesced f32 loads, one cvt each)
    double wv[16];
    #pragma unroll
    for (int hh = 0; hh < 16; ++hh)
      wv[hh] = (double)wp[(size_t)(c * 16 + hh) * En];
    #pragma unroll
    for (int hh = 0; hh < 16; ++hh) {
      #pragma unroll
      for (int j = 0; j < 4; ++j) {
        float xs = __int_as_float(
            __builtin_amdgcn_readlane(__float_as_int(xp), j * 16 + hh));
        acc[j] = fma((double)xs, wv[hh], acc[j]);
      }
    }
  }

  // combine H-halves: acc_full = half0 + half1 (fixed order), then softmax.
  #pragma unroll
  for (int j = 0; j < 4; ++j) red[w][j][lane] = acc[j];
  __syncthreads();

  double psum = 0.0;
  if (hf == 0) {
    const double bv = (double)Bv[lane];
    #pragma unroll
    for (int j = 0; j < 4; ++j) {
      double full = red[qd][j][lane] + red[qd + 2][j][lane] + bv;
      psum += wave_softmax_topk(full, g, t0 + j,
                                dkey, dlogz2, idx0, idx1, g0f, g1f);
    }
  }
  __syncthreads();
  red[0][w][lane] = psum;                          // waves 2,3 contribute 0
  __syncthreads();
  if (tid < 64) {
    double s = red[0][0][tid] + red[0][1][tid];
    partial[(size_t)bid * 64 + tid] = s;           // coalesced 512B
  }
}

// ---------------------------------------------------------------------------
// k2: stable descending rank, parallelized. 256 blocks; each block ranks
// 32 tokens against all Tn keys (staged once in LDS); 8 threads per token
// each scan 512 keys via b128 reads; integer partials summed exactly.
// ---------------------------------------------------------------------------
__global__ __launch_bounds__(256) void k2_rank(
    const double* __restrict__ dkey,
    const int* __restrict__ idx0, const int* __restrict__ idx1,
    int* __restrict__ perm, int* __restrict__ sidx0, int* __restrict__ sidx1)
{
  __shared__ __align__(16) double keys[Tn];        // 32 KB
  __shared__ int rk[32][8];
  const int tid = threadIdx.x;
  const int bid = blockIdx.x;
  const int g    = bid >> 7;                       // 128 blocks per group
  const int part = bid & 127;                      // 32 tokens per block
  const size_t gbase = (size_t)g * Tn;
  for (int i = tid; i < Tn; i += 256) keys[i] = dkey[gbase + i];
  __syncthreads();

  const int tl = tid >> 3;                         // token-local 0..31
  const int q  = tid & 7;                          // scan segment 0..7
  const int tg = part * 32 + tl;
  const double k = keys[tg];
  int r = 0;
  #pragma unroll 4
  for (int j2 = q * 512; j2 < q * 512 + 512; j2 += 2) {
    double2 kj = *(const double2*)&keys[j2];
    r += (kj.x > k) || (kj.x == k && (j2     < tg));
    r += (kj.y > k) || (kj.y == k && (j2 + 1 < tg));
  }
  rk[tl][q] = r;
  __syncthreads();
  if (tid < 32) {
    const int tg2 = part * 32 + tid;
    int rr = 0;
    #pragma unroll
    for (int u = 0; u < 8; ++u) rr += rk[tid][u];
    perm[gbase + rr]  = tg2;
    sidx0[gbase + rr] = idx0[gbase + tg2];
    sidx1[gbase + rr] = idx1[gbase + tg2];
  }
}

// ---------------------------------------------------------------------------
// k3 v2: exact cumsum priorities, block-parallel. One BLOCK per (g,e):
// 128 blocks x 256 threads. Each thread counts matches in its 16 consecutive
// sorted positions; Hillis-Steele block scan gives exclusive offsets; second
// pass assigns priorities (k=0 stream, then k=1 continuing the count —
// identical integers to the sequential ballot scan).
// ---------------------------------------------------------------------------
__global__ __launch_bounds__(256) void k3_prio(
    const int* __restrict__ sidx0, const int* __restrict__ sidx1,
    const int* __restrict__ perm,
    int* __restrict__ prio0, int* __restrict__ prio1, int* __restrict__ cntge)
{
  __shared__ int sc[256];
  const int tid = threadIdx.x;
  const int g = blockIdx.x >> 6;
  const int e = blockIdx.x & 63;
  const size_t gbase = (size_t)g * Tn;
  const int p0 = tid * 16;

  int base = 0;
  #pragma unroll
  for (int ph = 0; ph < 2; ++ph) {
    const int* __restrict__ sidx = ph ? sidx1 : sidx0;
    int* __restrict__ prio = ph ? prio1 : prio0;

    int loc[16];
    const int4* s4 = (const int4*)(sidx + gbase + p0);
    #pragma unroll
    for (int u = 0; u < 4; ++u) {
      int4 v = s4[u];
      loc[u * 4 + 0] = v.x; loc[u * 4 + 1] = v.y;
      loc[u * 4 + 2] = v.z; loc[u * 4 + 3] = v.w;
    }
    int cntl = 0;
    #pragma unroll
    for (int k = 0; k < 16; ++k) cntl += (loc[k] == e);

    __syncthreads();                   // protect sc reuse across phases
    sc[tid] = cntl;
    __syncthreads();
    #pragma unroll
    for (int off = 1; off < 256; off <<= 1) {
      int v = (tid >= off) ? sc[tid - off] : 0;
      __syncthreads();
      sc[tid] += v;
      __syncthreads();
    }
    int pr = base + sc[tid] - cntl;    // exclusive prefix + phase base
    int total = sc[255];
    #pragma unroll
    for (int k = 0; k < 16; ++k) {
      if (loc[k] == e) {
        prio[gbase + perm[gbase + p0 + k]] = pr;
        ++pr;
      }
    }
    base += total;
  }
  if (tid == 0) cntge[g * En + e] = base;
}

// ---------------------------------------------------------------------------
// k5a: per-group partials. Block g: zpart = sum(dlogz2[g]), auxpart =
// sum_e( cntge[g][e] * sum_b partial[b][e] ). Deterministic fixed trees.
// ---------------------------------------------------------------------------
__global__ __launch_bounds__(256) void k5a(
    const double* __restrict__ dlogz2, const double* __restrict__ partial,
    const int* __restrict__ cntge, double* __restrict__ gpart)
{
  __shared__ double red[256];
  const int g = blockIdx.x;
  const int tid = threadIdx.x;

  double z = 0.0;
  for (int i = tid; i < Tn; i += 256) z += dlogz2[(size_t)g * Tn + i];
  red[tid] = z; __syncthreads();
  for (int s = 128; s; s >>= 1) { if (tid < s) red[tid] += red[tid + s]; __syncthreads(); }
  if (tid == 0) gpart[g * 2 + 0] = red[0];
  __syncthreads();

  // sum partial over this group's 512 k1-blocks (coalesced 2KB per iter)
  const int q = tid >> 6, e = tid & 63;
  double s = 0.0;
  for (int i = 0; i < 128; ++i) {
    int b = g * 512 + i * 4 + q;
    s += partial[(size_t)b * 64 + e];
  }
  red[tid] = s; __syncthreads();
  if (tid < 64) {
    double sp = red[tid] + red[64 + tid] + red[128 + tid] + red[192 + tid];
    red[tid] = sp * (double)cntge[g * En + tid];
  }
  __syncthreads();
  for (int st = 32; st; st >>= 1) { if (tid < st) red[tid] += red[tid + st]; __syncthreads(); }
  if (tid == 0) gpart[g * 2 + 1] = red[0];
}

// ---------------------------------------------------------------------------
// k6 v2: sparse scatter only (zeros already written by k1). One thread per
// token writes its <=2 dispatch ones + <=2 combine gates. Thread 0 of
// block 0 finalizes the two scalar losses.
// ---------------------------------------------------------------------------
__global__ __launch_bounds__(256) void k6_fill(
    const int* __restrict__ idx0, const int* __restrict__ idx1,
    const int* __restrict__ prio0, const int* __restrict__ prio1,
    const float* __restrict__ g0f, const float* __restrict__ g1f,
    const double* __restrict__ gpart,
    float* __restrict__ out)
{
  const int t = blockIdx.x * 256 + threadIdx.x;    // 0..GT-1
  if (t < (int)GT) {
    const size_t gt = (size_t)t;
    const int e0 = idx0[gt], e1 = idx1[gt];
    const int p0 = prio0[gt], p1 = prio1[gt];
    const size_t slab = gt * (size_t)(En * CAPn);
    if (p0 < CAPn) {
      size_t n = slab + e0 * CAPn + p0;
      out[n] = 1.0f;
      out[GTEC + n] = g0f[gt];
    }
    if (p1 < CAPn) {
      size_t n = slab + e1 * CAPn + p1;
      out[n] = 1.0f;
      out[GTEC + n] = g1f[gt];
    }
  }
  if (t == 0) {
    double aux = (gpart[1] + gpart[3]) * (double)En /
                 ((double)Gn * (double)Tn * (double)Tn);
    double z   = (gpart[0] + gpart[2]) / (double)GT;
    out[GTEC * 2]     = (float)aux;
    out[GTEC * 2 + 1] = (float)z;
  }
}

// ---------------------------------------------------------------------------
extern "C" void kernel_launch(void* const* d_in, const int* in_sizes, int n_in,
                              void* d_out, int out_size, void* d_ws, size_t ws_size,
                              hipStream_t stream)
{
  (void)in_sizes; (void)n_in; (void)out_size; (void)ws_size;
  const float* X  = (const float*)d_in[0];   // [G,T,H]
  const float* W  = (const float*)d_in[1];   // [H,E]
  const float* Bv = (const float*)d_in[2];   // [E]
  float* out = (float*)d_out;

  char* ws = (char*)d_ws;
  size_t off = 0;
  auto carve = [&](size_t bytes) -> void* {
    void* p = ws + off;
    off += (bytes + 255) & ~(size_t)255;
    return p;
  };
  double* dkey    = (double*)carve(GT * 8);
  double* dlogz2  = (double*)carve(GT * 8);
  double* partial = (double*)carve((size_t)1024 * 64 * 8);  // 512 KB
  double* gpart   = (double*)carve(4 * 8);
  int* idx0  = (int*)carve(GT * 4);
  int* idx1  = (int*)carve(GT * 4);
  float* g0f = (float*)carve(GT * 4);
  float* g1f = (float*)carve(GT * 4);
  int* perm  = (int*)carve(GT * 4);
  int* sidx0 = (int*)carve(GT * 4);
  int* sidx1 = (int*)carve(GT * 4);
  int* prio0 = (int*)carve(GT * 4);
  int* prio1 = (int*)carve(GT * 4);
  int* cntge = (int*)carve((size_t)Gn * En * 4);

  k1_gemm<<<1024, 256, 0, stream>>>(X, W, Bv, dkey, dlogz2,
                                    idx0, idx1, g0f, g1f, partial, out);
  k2_rank<<<Gn * 128, 256, 0, stream>>>(dkey, idx0, idx1, perm, sidx0, sidx1);
  k3_prio<<<Gn * En, 256, 0, stream>>>(sidx0, sidx1, perm, prio0, prio1, cntge);
  k5a<<<Gn, 256, 0, stream>>>(dlogz2, partial, cntge, gpart);
  k6_fill<<<(int)(GT / 256), 256, 0, stream>>>(idx0, idx1, prio0, prio1,
                                               g0f, g1f, gpart, out);
}

// Round 10
// 162.041 us; speedup vs baseline: 3.0133x; 1.1018x over previous
//
#include <hip/hip_runtime.h>
#include <cstdint>
#include <cstddef>

static constexpr int Gn = 2;
static constexpr int Tn = 4096;
static constexpr int Hn = 2048;
static constexpr int En = 64;
static constexpr int CAPn = 128;
static constexpr size_t GT = (size_t)Gn * Tn;          // 8192
static constexpr size_t GTEC = GT * En * CAPn;         // 67,108,864
static constexpr size_t GTEC4 = GTEC / 4;              // float4 units

typedef float  f4v __attribute__((ext_vector_type(4)));  // NT-store vec
typedef double d4v __attribute__((ext_vector_type(4)));  // MFMA f64 acc

// ---------------------------------------------------------------------------
// Wave-level (64 lanes = 64 experts) softmax + top-2 + z-loss term, all f64.
// Returns p (this lane's expert probability) for the caller's aux-loss sum.
// Tie-breaking on equal probs: lower expert index wins (matches lax.top_k).
// ---------------------------------------------------------------------------
__device__ inline double wave_softmax_topk(
    double logit, int g, int t,
    double* __restrict__ dkey, double* __restrict__ dlogz2,
    int* __restrict__ idx0, int* __restrict__ idx1,
    float* __restrict__ g0f, float* __restrict__ g1f)
{
  const int e = threadIdx.x & 63;
  double m = logit;
  #pragma unroll
  for (int off = 32; off; off >>= 1) {
    double o = __shfl_xor(m, off);
    m = o > m ? o : m;
  }
  double ex = exp(logit - m);
  double s = ex;
  #pragma unroll
  for (int off = 32; off; off >>= 1) s += __shfl_xor(s, off);
  double p = ex / s;
  size_t gt = (size_t)g * Tn + t;

  // top-1 (value, index) with lower-index tie-break
  double bp = p; int bi = e;
  #pragma unroll
  for (int off = 32; off; off >>= 1) {
    double op = __shfl_xor(bp, off);
    int    oi = __shfl_xor(bi, off);
    if (op > bp || (op == bp && oi < bi)) { bp = op; bi = oi; }
  }
  // top-2: mask out top-1 lane
  double q = (e == bi) ? -1.0 : p;
  double bp2 = q; int bi2 = e;
  #pragma unroll
  for (int off = 32; off; off >>= 1) {
    double op = __shfl_xor(bp2, off);
    int    oi = __shfl_xor(bi2, off);
    if (op > bp2 || (op == bp2 && oi < bi2)) { bp2 = op; bi2 = oi; }
  }
  if (e == 0) {
    dkey[gt] = bp;                       // sort key = top-1 gate (f64)
    double lz = m + log(s);              // logsumexp
    dlogz2[gt] = lz * lz;
    idx0[gt] = bi;  idx1[gt] = bi2;
    g0f[gt] = (float)bp;  g1f[gt] = (float)bp2;
  }
  return p;
}

// ---------------------------------------------------------------------------
// k0_probe: empirically determine the f64 MFMA D-fragment layout.
// Probe 1: A[i][k]=i, B=1  => D[i][j] = 4i  -> rowmap[lane][r] = 4*row.
// Probe 2: A=1, B[k][j]=j  => D[i][j] = 4j  -> colmap[lane][r] = 4*col.
// Integer-exact in f64. Makes k1 correct under ANY row/col/reg permutation
// of the D fragment (the one cell the m89 verification never covered).
// ---------------------------------------------------------------------------
__global__ __launch_bounds__(64) void k0_probe(
    double* __restrict__ rowmap, double* __restrict__ colmap)
{
  const int lane = threadIdx.x & 63;
  const double ai = (double)(lane & 15);
  d4v accR = {0., 0., 0., 0.};
  d4v accC = {0., 0., 0., 0.};
  accR = __builtin_amdgcn_mfma_f64_16x16x4f64(ai, 1.0, accR, 0, 0, 0);
  accC = __builtin_amdgcn_mfma_f64_16x16x4f64(1.0, ai, accC, 0, 0, 0);
  #pragma unroll
  for (int r = 0; r < 4; ++r) {
    rowmap[lane * 4 + r] = accR[r];
    colmap[lane * 4 + r] = accC[r];
  }
}

// ---------------------------------------------------------------------------
// k1 v9: logits via v_mfma_f64_16x16x4_f64 (probe-corrected D layout) +
// softmax/top2 + prob-sum partials + output zero-fill.
// 512 blocks x 4 waves (2 blocks/CU). Block owns 16 tokens; wave w owns
// H-quarter w (512 h = 128 K-steps). A: lane=16k+i holds X[t0+i][h0+k];
// B: lane=16k+j holds W[h0+k][e0+j] (universal CDNA 16x16 operand layout,
// m89-verified on gfx950). D scatter goes through rowm/colm from k0_probe.
// Per K-step: 1 A-load + 4 B-loads + 5 cvt + 4 MFMA (4096 MACs) + 2 NT
// zero-stores (512 MB output fill rides along). H-quarters summed in fixed
// order via LDS (f64 reorder-safe, est. margins >=1e-7 vs noise 1e-15).
// ---------------------------------------------------------------------------
__global__ __launch_bounds__(256, 2) void k1_gemm(
    const float* __restrict__ X, const float* __restrict__ W,
    const float* __restrict__ Bv,
    const double* __restrict__ rowmap, const double* __restrict__ colmap,
    double* __restrict__ dkey, double* __restrict__ dlogz2,
    int* __restrict__ idx0, int* __restrict__ idx1,
    float* __restrict__ g0f, float* __restrict__ g1f,
    double* __restrict__ partial, float* __restrict__ out)
{
  __shared__ double lred[4][16][64];               // 32 KB partial logits
  __shared__ double pred[4][64];                   // 2 KB psum partials
  const int tid  = threadIdx.x;
  const int lane = tid & 63;
  const int w    = tid >> 6;                       // H-quarter
  const int bid  = blockIdx.x;
  const int g    = bid >> 8;                       // 256 blocks per group
  const int tb   = (bid & 255) * 16;               // block's first token
  const size_t gt0 = (size_t)g * Tn + tb;

  const int tl = lane & 15;                        // i (A-row) / j (B-col)
  const int kl = lane >> 4;                        // k within K=4

  int rowm[4], colm[4];
  #pragma unroll
  for (int r = 0; r < 4; ++r) {
    rowm[r] = (int)(rowmap[lane * 4 + r] * 0.25 + 0.5);
    colm[r] = (int)(colmap[lane * 4 + r] * 0.25 + 0.5);
  }

  // A: X[(gt0 + tl)*Hn + w*512 + 4*k4 + kl]
  const float* __restrict__ xa = X + (gt0 + tl) * Hn + w * 512 + kl;
  // B: W[(w*512 + 4*k4 + kl)*En + tl]  (+16/+32/+48 for e-tiles)
  const float* __restrict__ wb = W + (size_t)(w * 512 + kl) * En + tl;

  f4v* __restrict__ ob = (f4v*)out;
  const f4v zf = {0.f, 0.f, 0.f, 0.f};

  d4v acc0 = {0., 0., 0., 0.};
  d4v acc1 = {0., 0., 0., 0.};
  d4v acc2 = {0., 0., 0., 0.};
  d4v acc3 = {0., 0., 0., 0.};

  for (int k4 = 0; k4 < 128; ++k4) {
    // zero-fill: 2 coalesced NT stores/thread/step = block's 1 MB slabs
    {
      int n1 = k4 * 512 + tid;                     // [0, 65536)
      int n2 = n1 + 256;
      size_t i1 = (size_t)(n1 >> 15) * GTEC4 + gt0 * 2048 + (n1 & 32767);
      size_t i2 = (size_t)(n2 >> 15) * GTEC4 + gt0 * 2048 + (n2 & 32767);
      __builtin_nontemporal_store(zf, &ob[i1]);
      __builtin_nontemporal_store(zf, &ob[i2]);
    }
    double a = (double)xa[4 * k4];
    const float* wr = wb + (size_t)(4 * k4) * En;
    double b0 = (double)wr[0];
    double b1 = (double)wr[16];
    double b2 = (double)wr[32];
    double b3 = (double)wr[48];
    acc0 = __builtin_amdgcn_mfma_f64_16x16x4f64(a, b0, acc0, 0, 0, 0);
    acc1 = __builtin_amdgcn_mfma_f64_16x16x4f64(a, b1, acc1, 0, 0, 0);
    acc2 = __builtin_amdgcn_mfma_f64_16x16x4f64(a, b2, acc2, 0, 0, 0);
    acc3 = __builtin_amdgcn_mfma_f64_16x16x4f64(a, b3, acc3, 0, 0, 0);
  }

  // D[rowm[r]][colm[r] + 16*et] -> lred[w][token][expert] (probe-corrected)
  #pragma unroll
  for (int r = 0; r < 4; ++r) {
    lred[w][rowm[r]][colm[r]]      = acc0[r];
    lred[w][rowm[r]][16 + colm[r]] = acc1[r];
    lred[w][rowm[r]][32 + colm[r]] = acc2[r];
    lred[w][rowm[r]][48 + colm[r]] = acc3[r];
  }
  __syncthreads();

  // softmax/top2: wave w handles tokens 4w..4w+3; lane = expert.
  const double bv = (double)Bv[lane];
  double psum = 0.0;
  #pragma unroll
  for (int j = 0; j < 4; ++j) {
    int t = w * 4 + j;
    double full = lred[0][t][lane] + lred[1][t][lane]
                + lred[2][t][lane] + lred[3][t][lane] + bv;
    psum += wave_softmax_topk(full, g, tb + t,
                              dkey, dlogz2, idx0, idx1, g0f, g1f);
  }
  pred[w][lane] = psum;
  __syncthreads();
  if (tid < 64) {
    partial[(size_t)bid * 64 + tid] =
        pred[0][tid] + pred[1][tid] + pred[2][tid] + pred[3][tid];
  }
}

// ---------------------------------------------------------------------------
// k2: stable descending rank, parallelized. 256 blocks; each block ranks
// 32 tokens against all Tn keys (staged once in LDS); 8 threads per token
// each scan 512 keys via b128 reads; integer partials summed exactly.
// ---------------------------------------------------------------------------
__global__ __launch_bounds__(256) void k2_rank(
    const double* __restrict__ dkey,
    const int* __restrict__ idx0, const int* __restrict__ idx1,
    int* __restrict__ perm, int* __restrict__ sidx0, int* __restrict__ sidx1)
{
  __shared__ __align__(16) double keys[Tn];        // 32 KB
  __shared__ int rk[32][8];
  const int tid = threadIdx.x;
  const int bid = blockIdx.x;
  const int g    = bid >> 7;                       // 128 blocks per group
  const int part = bid & 127;                      // 32 tokens per block
  const size_t gbase = (size_t)g * Tn;
  for (int i = tid; i < Tn; i += 256) keys[i] = dkey[gbase + i];
  __syncthreads();

  const int tl = tid >> 3;                         // token-local 0..31
  const int q  = tid & 7;                          // scan segment 0..7
  const int tg = part * 32 + tl;
  const double k = keys[tg];
  int r = 0;
  #pragma unroll 4
  for (int j2 = q * 512; j2 < q * 512 + 512; j2 += 2) {
    double2 kj = *(const double2*)&keys[j2];
    r += (kj.x > k) || (kj.x == k && (j2     < tg));
    r += (kj.y > k) || (kj.y == k && (j2 + 1 < tg));
  }
  rk[tl][q] = r;
  __syncthreads();
  if (tid < 32) {
    const int tg2 = part * 32 + tid;
    int rr = 0;
    #pragma unroll
    for (int u = 0; u < 8; ++u) rr += rk[tid][u];
    perm[gbase + rr]  = tg2;
    sidx0[gbase + rr] = idx0[gbase + tg2];
    sidx1[gbase + rr] = idx1[gbase + tg2];
  }
}

// ---------------------------------------------------------------------------
// k3 v2: exact cumsum priorities, block-parallel. One BLOCK per (g,e):
// 128 blocks x 256 threads. Each thread counts matches in its 16 consecutive
// sorted positions; Hillis-Steele block scan gives exclusive offsets; second
// pass assigns priorities (k=0 stream, then k=1 continuing the count —
// identical integers to the sequential ballot scan).
// ---------------------------------------------------------------------------
__global__ __launch_bounds__(256) void k3_prio(
    const int* __restrict__ sidx0, const int* __restrict__ sidx1,
    const int* __restrict__ perm,
    int* __restrict__ prio0, int* __restrict__ prio1, int* __restrict__ cntge)
{
  __shared__ int sc[256];
  const int tid = threadIdx.x;
  const int g = blockIdx.x >> 6;
  const int e = blockIdx.x & 63;
  const size_t gbase = (size_t)g * Tn;
  const int p0 = tid * 16;

  int base = 0;
  #pragma unroll
  for (int ph = 0; ph < 2; ++ph) {
    const int* __restrict__ sidx = ph ? sidx1 : sidx0;
    int* __restrict__ prio = ph ? prio1 : prio0;

    int loc[16];
    const int4* s4 = (const int4*)(sidx + gbase + p0);
    #pragma unroll
    for (int u = 0; u < 4; ++u) {
      int4 v = s4[u];
      loc[u * 4 + 0] = v.x; loc[u * 4 + 1] = v.y;
      loc[u * 4 + 2] = v.z; loc[u * 4 + 3] = v.w;
    }
    int cntl = 0;
    #pragma unroll
    for (int k = 0; k < 16; ++k) cntl += (loc[k] == e);

    __syncthreads();                   // protect sc reuse across phases
    sc[tid] = cntl;
    __syncthreads();
    #pragma unroll
    for (int off = 1; off < 256; off <<= 1) {
      int v = (tid >= off) ? sc[tid - off] : 0;
      __syncthreads();
      sc[tid] += v;
      __syncthreads();
    }
    int pr = base + sc[tid] - cntl;    // exclusive prefix + phase base
    int total = sc[255];
    #pragma unroll
    for (int k = 0; k < 16; ++k) {
      if (loc[k] == e) {
        prio[gbase + perm[gbase + p0 + k]] = pr;
        ++pr;
      }
    }
    base += total;
  }
  if (tid == 0) cntge[g * En + e] = base;
}

// ---------------------------------------------------------------------------
// k5a: per-group partials. Block g: zpart = sum(dlogz2[g]), auxpart =
// sum_e( cntge[g][e] * sum_b partial[b][e] ). Deterministic fixed trees.
// ---------------------------------------------------------------------------
__global__ __launch_bounds__(256) void k5a(
    const double* __restrict__ dlogz2, const double* __restrict__ partial,
    const int* __restrict__ cntge, double* __restrict__ gpart)
{
  __shared__ double red[256];
  const int g = blockIdx.x;
  const int tid = threadIdx.x;

  double z = 0.0;
  for (int i = tid; i < Tn; i += 256) z += dlogz2[(size_t)g * Tn + i];
  red[tid] = z; __syncthreads();
  for (int s = 128; s; s >>= 1) { if (tid < s) red[tid] += red[tid + s]; __syncthreads(); }
  if (tid == 0) gpart[g * 2 + 0] = red[0];
  __syncthreads();

  // sum partial over this group's 256 k1-blocks (coalesced 2KB per iter)
  const int q = tid >> 6, e = tid & 63;
  double s = 0.0;
  for (int i = 0; i < 64; ++i) {
    int b = g * 256 + i * 4 + q;
    s += partial[(size_t)b * 64 + e];
  }
  red[tid] = s; __syncthreads();
  if (tid < 64) {
    double sp = red[tid] + red[64 + tid] + red[128 + tid] + red[192 + tid];
    red[tid] = sp * (double)cntge[g * En + tid];
  }
  __syncthreads();
  for (int st = 32; st; st >>= 1) { if (tid < st) red[tid] += red[tid + st]; __syncthreads(); }
  if (tid == 0) gpart[g * 2 + 1] = red[0];
}

// ---------------------------------------------------------------------------
// k6 v2: sparse scatter only (zeros already written by k1). One thread per
// token writes its <=2 dispatch ones + <=2 combine gates. Thread 0 of
// block 0 finalizes the two scalar losses.
// ---------------------------------------------------------------------------
__global__ __launch_bounds__(256) void k6_fill(
    const int* __restrict__ idx0, const int* __restrict__ idx1,
    const int* __restrict__ prio0, const int* __restrict__ prio1,
    const float* __restrict__ g0f, const float* __restrict__ g1f,
    const double* __restrict__ gpart,
    float* __restrict__ out)
{
  const int t = blockIdx.x * 256 + threadIdx.x;    // 0..GT-1
  if (t < (int)GT) {
    const size_t gt = (size_t)t;
    const int e0 = idx0[gt], e1 = idx1[gt];
    const int p0 = prio0[gt], p1 = prio1[gt];
    const size_t slab = gt * (size_t)(En * CAPn);
    if (p0 < CAPn) {
      size_t n = slab + e0 * CAPn + p0;
      out[n] = 1.0f;
      out[GTEC + n] = g0f[gt];
    }
    if (p1 < CAPn) {
      size_t n = slab + e1 * CAPn + p1;
      out[n] = 1.0f;
      out[GTEC + n] = g1f[gt];
    }
  }
  if (t == 0) {
    double aux = (gpart[1] + gpart[3]) * (double)En /
                 ((double)Gn * (double)Tn * (double)Tn);
    double z   = (gpart[0] + gpart[2]) / (double)GT;
    out[GTEC * 2]     = (float)aux;
    out[GTEC * 2 + 1] = (float)z;
  }
}

// ---------------------------------------------------------------------------
extern "C" void kernel_launch(void* const* d_in, const int* in_sizes, int n_in,
                              void* d_out, int out_size, void* d_ws, size_t ws_size,
                              hipStream_t stream)
{
  (void)in_sizes; (void)n_in; (void)out_size; (void)ws_size;
  const float* X  = (const float*)d_in[0];   // [G,T,H]
  const float* W  = (const float*)d_in[1];   // [H,E]
  const float* Bv = (const float*)d_in[2];   // [E]
  float* out = (float*)d_out;

  char* ws = (char*)d_ws;
  size_t off = 0;
  auto carve = [&](size_t bytes) -> void* {
    void* p = ws + off;
    off += (bytes + 255) & ~(size_t)255;
    return p;
  };
  double* rowmap  = (double*)carve(64 * 4 * 8);
  double* colmap  = (double*)carve(64 * 4 * 8);
  double* dkey    = (double*)carve(GT * 8);
  double* dlogz2  = (double*)carve(GT * 8);
  double* partial = (double*)carve((size_t)512 * 64 * 8);  // 256 KB
  double* gpart   = (double*)carve(4 * 8);
  int* idx0  = (int*)carve(GT * 4);
  int* idx1  = (int*)carve(GT * 4);
  float* g0f = (float*)carve(GT * 4);
  float* g1f = (float*)carve(GT * 4);
  int* perm  = (int*)carve(GT * 4);
  int* sidx0 = (int*)carve(GT * 4);
  int* sidx1 = (int*)carve(GT * 4);
  int* prio0 = (int*)carve(GT * 4);
  int* prio1 = (int*)carve(GT * 4);
  int* cntge = (int*)carve((size_t)Gn * En * 4);

  k0_probe<<<1, 64, 0, stream>>>(rowmap, colmap);
  k1_gemm<<<512, 256, 0, stream>>>(X, W, Bv, rowmap, colmap, dkey, dlogz2,
                                   idx0, idx1, g0f, g1f, partial, out);
  k2_rank<<<Gn * 128, 256, 0, stream>>>(dkey, idx0, idx1, perm, sidx0, sidx1);
  k3_prio<<<Gn * En, 256, 0, stream>>>(sidx0, sidx1, perm, prio0, prio1, cntge);
  k5a<<<Gn, 256, 0, stream>>>(dlogz2, partial, cntge, gpart);
  k6_fill<<<(int)(GT / 256), 256, 0, stream>>>(idx0, idx1, prio0, prio1,
                                               g0f, g1f, gpart, out);
}

// Round 11
// 151.830 us; speedup vs baseline: 3.2160x; 1.0673x over previous
//
#include <hip/hip_runtime.h>
#include <cstdint>
#include <cstddef>

static constexpr int Gn = 2;
static constexpr int Tn = 4096;
static constexpr int Hn = 2048;
static constexpr int En = 64;
static constexpr int CAPn = 128;
static constexpr size_t GT = (size_t)Gn * Tn;          // 8192
static constexpr size_t GTEC = GT * En * CAPn;         // 67,108,864
static constexpr size_t GTEC4 = GTEC / 4;              // float4 units

typedef float  f4v __attribute__((ext_vector_type(4)));  // NT-store vec
typedef double d4v __attribute__((ext_vector_type(4)));  // MFMA f64 acc

// ---------------------------------------------------------------------------
// Wave-level (64 lanes = 64 experts) softmax + top-2 + z-loss term, all f64.
// Returns p (this lane's expert probability) for the caller's aux-loss sum.
// Tie-breaking on equal probs: lower expert index wins (matches lax.top_k).
// ---------------------------------------------------------------------------
__device__ inline double wave_softmax_topk(
    double logit, int g, int t,
    double* __restrict__ dkey, double* __restrict__ dlogz2,
    int* __restrict__ idx0, int* __restrict__ idx1,
    float* __restrict__ g0f, float* __restrict__ g1f)
{
  const int e = threadIdx.x & 63;
  double m = logit;
  #pragma unroll
  for (int off = 32; off; off >>= 1) {
    double o = __shfl_xor(m, off);
    m = o > m ? o : m;
  }
  double ex = exp(logit - m);
  double s = ex;
  #pragma unroll
  for (int off = 32; off; off >>= 1) s += __shfl_xor(s, off);
  double p = ex / s;
  size_t gt = (size_t)g * Tn + t;

  // top-1 (value, index) with lower-index tie-break
  double bp = p; int bi = e;
  #pragma unroll
  for (int off = 32; off; off >>= 1) {
    double op = __shfl_xor(bp, off);
    int    oi = __shfl_xor(bi, off);
    if (op > bp || (op == bp && oi < bi)) { bp = op; bi = oi; }
  }
  // top-2: mask out top-1 lane
  double q = (e == bi) ? -1.0 : p;
  double bp2 = q; int bi2 = e;
  #pragma unroll
  for (int off = 32; off; off >>= 1) {
    double op = __shfl_xor(bp2, off);
    int    oi = __shfl_xor(bi2, off);
    if (op > bp2 || (op == bp2 && oi < bi2)) { bp2 = op; bi2 = oi; }
  }
  if (e == 0) {
    dkey[gt] = bp;                       // sort key = top-1 gate (f64)
    double lz = m + log(s);              // logsumexp
    dlogz2[gt] = lz * lz;
    idx0[gt] = bi;  idx1[gt] = bi2;
    g0f[gt] = (float)bp;  g1f[gt] = (float)bp2;
  }
  return p;
}

// ---------------------------------------------------------------------------
// k0_probe: empirically determine the f64 MFMA D-fragment layout.
// Probe 1: A[i][k]=i, B=1  => D[i][j] = 4i  -> rowmap[lane][r] = 4*row.
// Probe 2: A=1, B[k][j]=j  => D[i][j] = 4j  -> colmap[lane][r] = 4*col.
// Integer-exact in f64; makes k1 correct under ANY D permutation.
// ---------------------------------------------------------------------------
__global__ __launch_bounds__(64) void k0_probe(
    double* __restrict__ rowmap, double* __restrict__ colmap)
{
  const int lane = threadIdx.x & 63;
  const double ai = (double)(lane & 15);
  d4v accR = {0., 0., 0., 0.};
  d4v accC = {0., 0., 0., 0.};
  accR = __builtin_amdgcn_mfma_f64_16x16x4f64(ai, 1.0, accR, 0, 0, 0);
  accC = __builtin_amdgcn_mfma_f64_16x16x4f64(1.0, ai, accC, 0, 0, 0);
  #pragma unroll
  for (int r = 0; r < 4; ++r) {
    rowmap[lane * 4 + r] = accR[r];
    colmap[lane * 4 + r] = accC[r];
  }
}

// ---------------------------------------------------------------------------
// k1 v10: f64-MFMA logits + softmax/top2 + prob-sum partials + zero-fill.
// 512 blocks x 8 waves (512 thr) = 2 blocks/CU, 4 waves/SIMD (TLP doubled
// vs v9 so store/load/MFMA pipes overlap across waves). Block owns 16
// tokens; wave w owns H-eighth w (256 h = 64 K-steps).
// A: lane=16k+i holds X[t0+i][h0+k]; B: lane=16k+j holds W[h0+k][e0+j];
// D scattered via probe-derived rowm/colm. Per K-step: 1 A-load + 4
// B-loads + 5 cvt + 4 MFMA (4096 MACs) + 2 NT zero-stores.
// H-eighths summed in fixed order via LDS (f64 reorder-safe, cf. R8/R10).
// ---------------------------------------------------------------------------
__global__ __launch_bounds__(512, 4) void k1_gemm(
    const float* __restrict__ X, const float* __restrict__ W,
    const float* __restrict__ Bv,
    const double* __restrict__ rowmap, const double* __restrict__ colmap,
    double* __restrict__ dkey, double* __restrict__ dlogz2,
    int* __restrict__ idx0, int* __restrict__ idx1,
    float* __restrict__ g0f, float* __restrict__ g1f,
    double* __restrict__ partial, float* __restrict__ out)
{
  __shared__ double lred[8][16][64];               // 64 KB partial logits
  __shared__ double pred[8][64];                   // 4 KB psum partials
  const int tid  = threadIdx.x;
  const int lane = tid & 63;
  const int w    = tid >> 6;                       // H-eighth 0..7
  const int bid  = blockIdx.x;
  const int g    = bid >> 8;                       // 256 blocks per group
  const int tb   = (bid & 255) * 16;               // block's first token
  const size_t gt0 = (size_t)g * Tn + tb;

  const int tl = lane & 15;                        // i (A-row) / j (B-col)
  const int kl = lane >> 4;                        // k within K=4

  int rowm[4], colm[4];
  #pragma unroll
  for (int r = 0; r < 4; ++r) {
    rowm[r] = (int)(rowmap[lane * 4 + r] * 0.25 + 0.5);
    colm[r] = (int)(colmap[lane * 4 + r] * 0.25 + 0.5);
  }

  // A: X[(gt0 + tl)*Hn + w*256 + 4*k4 + kl]
  const float* __restrict__ xa = X + (gt0 + tl) * Hn + w * 256 + kl;
  // B: W[(w*256 + 4*k4 + kl)*En + tl]  (+16/+32/+48 for e-tiles)
  const float* __restrict__ wb = W + (size_t)(w * 256 + kl) * En + tl;

  f4v* __restrict__ ob = (f4v*)out;
  const f4v zf = {0.f, 0.f, 0.f, 0.f};

  d4v acc0 = {0., 0., 0., 0.};
  d4v acc1 = {0., 0., 0., 0.};
  d4v acc2 = {0., 0., 0., 0.};
  d4v acc3 = {0., 0., 0., 0.};

  for (int k4 = 0; k4 < 64; ++k4) {
    // zero-fill: 2 coalesced NT stores/thread/step = block's 1 MiB slabs
    {
      int n1 = k4 * 1024 + tid;                    // [0, 65536)
      int n2 = n1 + 512;
      size_t i1 = (size_t)(n1 >> 15) * GTEC4 + gt0 * 2048 + (n1 & 32767);
      size_t i2 = (size_t)(n2 >> 15) * GTEC4 + gt0 * 2048 + (n2 & 32767);
      __builtin_nontemporal_store(zf, &ob[i1]);
      __builtin_nontemporal_store(zf, &ob[i2]);
    }
    double a = (double)xa[4 * k4];
    const float* wr = wb + (size_t)(4 * k4) * En;
    double b0 = (double)wr[0];
    double b1 = (double)wr[16];
    double b2 = (double)wr[32];
    double b3 = (double)wr[48];
    acc0 = __builtin_amdgcn_mfma_f64_16x16x4f64(a, b0, acc0, 0, 0, 0);
    acc1 = __builtin_amdgcn_mfma_f64_16x16x4f64(a, b1, acc1, 0, 0, 0);
    acc2 = __builtin_amdgcn_mfma_f64_16x16x4f64(a, b2, acc2, 0, 0, 0);
    acc3 = __builtin_amdgcn_mfma_f64_16x16x4f64(a, b3, acc3, 0, 0, 0);
  }

  // D[rowm[r]][colm[r] + 16*et] -> lred[w][token][expert] (probe-corrected)
  #pragma unroll
  for (int r = 0; r < 4; ++r) {
    lred[w][rowm[r]][colm[r]]      = acc0[r];
    lred[w][rowm[r]][16 + colm[r]] = acc1[r];
    lred[w][rowm[r]][32 + colm[r]] = acc2[r];
    lred[w][rowm[r]][48 + colm[r]] = acc3[r];
  }
  __syncthreads();

  // softmax/top2: wave w handles tokens 2w, 2w+1; lane = expert.
  const double bv = (double)Bv[lane];
  double psum = 0.0;
  #pragma unroll
  for (int j = 0; j < 2; ++j) {
    int t = w * 2 + j;
    double full = lred[0][t][lane] + lred[1][t][lane]
                + lred[2][t][lane] + lred[3][t][lane]
                + lred[4][t][lane] + lred[5][t][lane]
                + lred[6][t][lane] + lred[7][t][lane] + bv;
    psum += wave_softmax_topk(full, g, tb + t,
                              dkey, dlogz2, idx0, idx1, g0f, g1f);
  }
  pred[w][lane] = psum;
  __syncthreads();
  if (tid < 64) {
    double s = pred[0][tid] + pred[1][tid] + pred[2][tid] + pred[3][tid]
             + pred[4][tid] + pred[5][tid] + pred[6][tid] + pred[7][tid];
    partial[(size_t)bid * 64 + tid] = s;           // coalesced 512B
  }
}

// ---------------------------------------------------------------------------
// k2: stable descending rank, parallelized. 256 blocks; each block ranks
// 32 tokens against all Tn keys (staged once in LDS); 8 threads per token
// each scan 512 keys via b128 reads; integer partials summed exactly.
// ---------------------------------------------------------------------------
__global__ __launch_bounds__(256) void k2_rank(
    const double* __restrict__ dkey,
    const int* __restrict__ idx0, const int* __restrict__ idx1,
    int* __restrict__ perm, int* __restrict__ sidx0, int* __restrict__ sidx1)
{
  __shared__ __align__(16) double keys[Tn];        // 32 KB
  __shared__ int rk[32][8];
  const int tid = threadIdx.x;
  const int bid = blockIdx.x;
  const int g    = bid >> 7;                       // 128 blocks per group
  const int part = bid & 127;                      // 32 tokens per block
  const size_t gbase = (size_t)g * Tn;
  for (int i = tid; i < Tn; i += 256) keys[i] = dkey[gbase + i];
  __syncthreads();

  const int tl = tid >> 3;                         // token-local 0..31
  const int q  = tid & 7;                          // scan segment 0..7
  const int tg = part * 32 + tl;
  const double k = keys[tg];
  int r = 0;
  #pragma unroll 4
  for (int j2 = q * 512; j2 < q * 512 + 512; j2 += 2) {
    double2 kj = *(const double2*)&keys[j2];
    r += (kj.x > k) || (kj.x == k && (j2     < tg));
    r += (kj.y > k) || (kj.y == k && (j2 + 1 < tg));
  }
  rk[tl][q] = r;
  __syncthreads();
  if (tid < 32) {
    const int tg2 = part * 32 + tid;
    int rr = 0;
    #pragma unroll
    for (int u = 0; u < 8; ++u) rr += rk[tid][u];
    perm[gbase + rr]  = tg2;
    sidx0[gbase + rr] = idx0[gbase + tg2];
    sidx1[gbase + rr] = idx1[gbase + tg2];
  }
}

// ---------------------------------------------------------------------------
// k3 v2: exact cumsum priorities, block-parallel. One BLOCK per (g,e):
// 128 blocks x 256 threads. Each thread counts matches in its 16 consecutive
// sorted positions; Hillis-Steele block scan gives exclusive offsets; second
// pass assigns priorities (k=0 stream, then k=1 continuing the count —
// identical integers to the sequential ballot scan).
// ---------------------------------------------------------------------------
__global__ __launch_bounds__(256) void k3_prio(
    const int* __restrict__ sidx0, const int* __restrict__ sidx1,
    const int* __restrict__ perm,
    int* __restrict__ prio0, int* __restrict__ prio1, int* __restrict__ cntge)
{
  __shared__ int sc[256];
  const int tid = threadIdx.x;
  const int g = blockIdx.x >> 6;
  const int e = blockIdx.x & 63;
  const size_t gbase = (size_t)g * Tn;
  const int p0 = tid * 16;

  int base = 0;
  #pragma unroll
  for (int ph = 0; ph < 2; ++ph) {
    const int* __restrict__ sidx = ph ? sidx1 : sidx0;
    int* __restrict__ prio = ph ? prio1 : prio0;

    int loc[16];
    const int4* s4 = (const int4*)(sidx + gbase + p0);
    #pragma unroll
    for (int u = 0; u < 4; ++u) {
      int4 v = s4[u];
      loc[u * 4 + 0] = v.x; loc[u * 4 + 1] = v.y;
      loc[u * 4 + 2] = v.z; loc[u * 4 + 3] = v.w;
    }
    int cntl = 0;
    #pragma unroll
    for (int k = 0; k < 16; ++k) cntl += (loc[k] == e);

    __syncthreads();                   // protect sc reuse across phases
    sc[tid] = cntl;
    __syncthreads();
    #pragma unroll
    for (int off = 1; off < 256; off <<= 1) {
      int v = (tid >= off) ? sc[tid - off] : 0;
      __syncthreads();
      sc[tid] += v;
      __syncthreads();
    }
    int pr = base + sc[tid] - cntl;    // exclusive prefix + phase base
    int total = sc[255];
    #pragma unroll
    for (int k = 0; k < 16; ++k) {
      if (loc[k] == e) {
        prio[gbase + perm[gbase + p0 + k]] = pr;
        ++pr;
      }
    }
    base += total;
  }
  if (tid == 0) cntge[g * En + e] = base;
}

// ---------------------------------------------------------------------------
// k5a: per-group partials. Block g: zpart = sum(dlogz2[g]), auxpart =
// sum_e( cntge[g][e] * sum_b partial[b][e] ). Deterministic fixed trees.
// ---------------------------------------------------------------------------
__global__ __launch_bounds__(256) void k5a(
    const double* __restrict__ dlogz2, const double* __restrict__ partial,
    const int* __restrict__ cntge, double* __restrict__ gpart)
{
  __shared__ double red[256];
  const int g = blockIdx.x;
  const int tid = threadIdx.x;

  double z = 0.0;
  for (int i = tid; i < Tn; i += 256) z += dlogz2[(size_t)g * Tn + i];
  red[tid] = z; __syncthreads();
  for (int s = 128; s; s >>= 1) { if (tid < s) red[tid] += red[tid + s]; __syncthreads(); }
  if (tid == 0) gpart[g * 2 + 0] = red[0];
  __syncthreads();

  // sum partial over this group's 256 k1-blocks (coalesced 2KB per iter)
  const int q = tid >> 6, e = tid & 63;
  double s = 0.0;
  for (int i = 0; i < 64; ++i) {
    int b = g * 256 + i * 4 + q;
    s += partial[(size_t)b * 64 + e];
  }
  red[tid] = s; __syncthreads();
  if (tid < 64) {
    double sp = red[tid] + red[64 + tid] + red[128 + tid] + red[192 + tid];
    red[tid] = sp * (double)cntge[g * En + tid];
  }
  __syncthreads();
  for (int st = 32; st; st >>= 1) { if (tid < st) red[tid] += red[tid + st]; __syncthreads(); }
  if (tid == 0) gpart[g * 2 + 1] = red[0];
}

// ---------------------------------------------------------------------------
// k6 v2: sparse scatter only (zeros already written by k1). One thread per
// token writes its <=2 dispatch ones + <=2 combine gates. Thread 0 of
// block 0 finalizes the two scalar losses.
// ---------------------------------------------------------------------------
__global__ __launch_bounds__(256) void k6_fill(
    const int* __restrict__ idx0, const int* __restrict__ idx1,
    const int* __restrict__ prio0, const int* __restrict__ prio1,
    const float* __restrict__ g0f, const float* __restrict__ g1f,
    const double* __restrict__ gpart,
    float* __restrict__ out)
{
  const int t = blockIdx.x * 256 + threadIdx.x;    // 0..GT-1
  if (t < (int)GT) {
    const size_t gt = (size_t)t;
    const int e0 = idx0[gt], e1 = idx1[gt];
    const int p0 = prio0[gt], p1 = prio1[gt];
    const size_t slab = gt * (size_t)(En * CAPn);
    if (p0 < CAPn) {
      size_t n = slab + e0 * CAPn + p0;
      out[n] = 1.0f;
      out[GTEC + n] = g0f[gt];
    }
    if (p1 < CAPn) {
      size_t n = slab + e1 * CAPn + p1;
      out[n] = 1.0f;
      out[GTEC + n] = g1f[gt];
    }
  }
  if (t == 0) {
    double aux = (gpart[1] + gpart[3]) * (double)En /
                 ((double)Gn * (double)Tn * (double)Tn);
    double z   = (gpart[0] + gpart[2]) / (double)GT;
    out[GTEC * 2]     = (float)aux;
    out[GTEC * 2 + 1] = (float)z;
  }
}

// ---------------------------------------------------------------------------
extern "C" void kernel_launch(void* const* d_in, const int* in_sizes, int n_in,
                              void* d_out, int out_size, void* d_ws, size_t ws_size,
                              hipStream_t stream)
{
  (void)in_sizes; (void)n_in; (void)out_size; (void)ws_size;
  const float* X  = (const float*)d_in[0];   // [G,T,H]
  const float* W  = (const float*)d_in[1];   // [H,E]
  const float* Bv = (const float*)d_in[2];   // [E]
  float* out = (float*)d_out;

  char* ws = (char*)d_ws;
  size_t off = 0;
  auto carve = [&](size_t bytes) -> void* {
    void* p = ws + off;
    off += (bytes + 255) & ~(size_t)255;
    return p;
  };
  double* rowmap  = (double*)carve(64 * 4 * 8);
  double* colmap  = (double*)carve(64 * 4 * 8);
  double* dkey    = (double*)carve(GT * 8);
  double* dlogz2  = (double*)carve(GT * 8);
  double* partial = (double*)carve((size_t)512 * 64 * 8);  // 256 KB
  double* gpart   = (double*)carve(4 * 8);
  int* idx0  = (int*)carve(GT * 4);
  int* idx1  = (int*)carve(GT * 4);
  float* g0f = (float*)carve(GT * 4);
  float* g1f = (float*)carve(GT * 4);
  int* perm  = (int*)carve(GT * 4);
  int* sidx0 = (int*)carve(GT * 4);
  int* sidx1 = (int*)carve(GT * 4);
  int* prio0 = (int*)carve(GT * 4);
  int* prio1 = (int*)carve(GT * 4);
  int* cntge = (int*)carve((size_t)Gn * En * 4);

  k0_probe<<<1, 64, 0, stream>>>(rowmap, colmap);
  k1_gemm<<<512, 512, 0, stream>>>(X, W, Bv, rowmap, colmap, dkey, dlogz2,
                                   idx0, idx1, g0f, g1f, partial, out);
  k2_rank<<<Gn * 128, 256, 0, stream>>>(dkey, idx0, idx1, perm, sidx0, sidx1);
  k3_prio<<<Gn * En, 256, 0, stream>>>(sidx0, sidx1, perm, prio0, prio1, cntge);
  k5a<<<Gn, 256, 0, stream>>>(dlogz2, partial, cntge, gpart);
  k6_fill<<<(int)(GT / 256), 256, 0, stream>>>(idx0, idx1, prio0, prio1,
                                               g0f, g1f, gpart, out);
}